// Round 4
// baseline (1005.373 us; speedup 1.0000x reference)
//
#include <hip/hip_runtime.h>
#include <cstdint>
#include <cstddef>

typedef __bf16 bf16;
typedef __bf16 bf16x4 __attribute__((ext_vector_type(4)));
typedef __bf16 bf16x8 __attribute__((ext_vector_type(8)));
typedef float  f32x4  __attribute__((ext_vector_type(4)));

#define GLD_LDS16(gp, lp) \
  __builtin_amdgcn_global_load_lds((__attribute__((address_space(1))) void*)(gp), \
                                   (__attribute__((address_space(3))) void*)(lp), 16, 0, 0)

__device__ __forceinline__ f32x4 f32x4_zero(){ f32x4 v; v[0]=0.f; v[1]=0.f; v[2]=0.f; v[3]=0.f; return v; }

__device__ __forceinline__ f32x4 mfma16x16x32(bf16x8 a, bf16x8 b, f32x4 c){
  return __builtin_amdgcn_mfma_f32_16x16x32_bf16(a, b, c, 0, 0, 0);
}
// fragment of a 64x64 bf16 LDS array, A/B-operand layout for 16x16x32
__device__ __forceinline__ bf16x8 frag64(const bf16* base, int row0, int kk, int lane){
  return *(const bf16x8*)&base[(row0 + (lane&15))*64 + kk*32 + (lane>>4)*8];
}
struct bf2 { bf16 h, l; };
__device__ __forceinline__ bf2 split2(float v){
  bf2 r; r.h = (bf16)v; r.l = (bf16)(v - (float)r.h); return r;
}

// ---------------------------------------------------------------- K0a: x -> hi/lo bf16 planes
__global__ __launch_bounds__(256) void k_cvt_x(const float* __restrict__ x,
                                               bf16* __restrict__ xh, bf16* __restrict__ xl, int n4){
  int i = blockIdx.x*256 + threadIdx.x;
  if (i < n4){
    float4 v = ((const float4*)x)[i];
    bf16x4 h, l;
    bf2 t0 = split2(v.x); h[0]=t0.h; l[0]=t0.l;
    bf2 t1 = split2(v.y); h[1]=t1.h; l[1]=t1.l;
    bf2 t2 = split2(v.z); h[2]=t2.h; l[2]=t2.l;
    bf2 t3 = split2(v.w); h[3]=t3.h; l[3]=t3.l;
    ((bf16x4*)xh)[i] = h;
    ((bf16x4*)xl)[i] = l;
  }
}

// ---------------------------------------------------------------- K0b: W[k][n] -> Wt hi/lo [n][k]
__global__ __launch_bounds__(256) void k_transpose_w(const float* __restrict__ W,
                                                     bf16* __restrict__ Wth, bf16* __restrict__ Wtl){
  __shared__ float tile[32][33];
  const int k0 = blockIdx.x*32, n0 = blockIdx.y*32;
  const int r = threadIdx.x >> 3, c4 = (threadIdx.x & 7)*4;
  float4 v = *(const float4*)&W[(size_t)(k0+r)*1024 + n0 + c4];
  tile[r][c4+0]=v.x; tile[r][c4+1]=v.y; tile[r][c4+2]=v.z; tile[r][c4+3]=v.w;
  __syncthreads();
  bf16x4 h, l;
  bf2 t0 = split2(tile[c4+0][r]); h[0]=t0.h; l[0]=t0.l;
  bf2 t1 = split2(tile[c4+1][r]); h[1]=t1.h; l[1]=t1.l;
  bf2 t2 = split2(tile[c4+2][r]); h[2]=t2.h; l[2]=t2.l;
  bf2 t3 = split2(tile[c4+3][r]); h[3]=t3.h; l[3]=t3.l;
  *(bf16x4*)&Wth[(size_t)(n0+r)*1024 + k0 + c4] = h;
  *(bf16x4*)&Wtl[(size_t)(n0+r)*1024 + k0 + c4] = l;
}

// ---------------------------------------------------------------- K0c: Walpha/Wbeta [1024][16] -> [16][1024] fp32
__global__ __launch_bounds__(256) void k_transpose_ab(const float* __restrict__ Wa, const float* __restrict__ Wb,
                                                      float* __restrict__ WaT, float* __restrict__ WbT){
  int p = blockIdx.x*256 + threadIdx.x;
  if (p < 16384){
    int o = p >> 10, k = p & 1023;
    WaT[p] = Wa[k*16 + o];
    WbT[p] = Wb[k*16 + o];
  }
}

// ---------------------------------------------------------------- K1: split-bf16 MFMA GEMM (3-product), K=1024
// A = Ah+Al [M][1024]; B^T = Bth+Btl [N][1024]. One of Cb (bf16) / Cf (fp32) non-null.
__global__ __launch_bounds__(256) void k_gemm3(const bf16* __restrict__ Ah, const bf16* __restrict__ Al,
                                               const bf16* __restrict__ Bth, const bf16* __restrict__ Btl,
                                               bf16* __restrict__ Cb, float* __restrict__ Cf){
  __shared__ bf16 Ash[128*32], Asl[128*32];
  __shared__ bf16 Bsh[128*32], Bsl[128*32];
  const int tid = threadIdx.x, lane = tid & 63, w = tid >> 6;
  const int wm = w >> 1, wn = w & 1;
  const size_t m0 = (size_t)blockIdx.x * 128;
  const size_t n0 = (size_t)blockIdx.y * 128;
  f32x4 acc[4][4];
  #pragma unroll
  for (int i=0;i<4;++i)
    #pragma unroll
    for (int j=0;j<4;++j) acc[i][j] = f32x4_zero();

  for (int k0 = 0; k0 < 1024; k0 += 32){
    __syncthreads();
    #pragma unroll
    for (int j = 0; j < 2; ++j){
      const int rbase = 32*w + 16*j;
      const int r = rbase + (lane >> 2);
      const int kk = k0 + (lane & 3)*8;
      GLD_LDS16(&Ah [(m0 + r)*1024 + kk], &Ash[rbase*32]);
      GLD_LDS16(&Al [(m0 + r)*1024 + kk], &Asl[rbase*32]);
      GLD_LDS16(&Bth[(n0 + r)*1024 + kk], &Bsh[rbase*32]);
      GLD_LDS16(&Btl[(n0 + r)*1024 + kk], &Bsl[rbase*32]);
    }
    __syncthreads();
    bf16x8 ah[4], al[4], bh[4], bl[4];
    #pragma unroll
    for (int t=0;t<4;++t){
      ah[t] = *(const bf16x8*)&Ash[(64*wm + 16*t + (lane&15))*32 + (lane>>4)*8];
      al[t] = *(const bf16x8*)&Asl[(64*wm + 16*t + (lane&15))*32 + (lane>>4)*8];
      bh[t] = *(const bf16x8*)&Bsh[(64*wn + 16*t + (lane&15))*32 + (lane>>4)*8];
      bl[t] = *(const bf16x8*)&Bsl[(64*wn + 16*t + (lane&15))*32 + (lane>>4)*8];
    }
    #pragma unroll
    for (int i=0;i<4;++i)
      #pragma unroll
      for (int j=0;j<4;++j){
        f32x4 t = acc[i][j];
        t = mfma16x16x32(ah[i], bh[j], t);
        t = mfma16x16x32(ah[i], bl[j], t);
        t = mfma16x16x32(al[i], bh[j], t);
        acc[i][j] = t;
      }
  }
  #pragma unroll
  for (int i=0;i<4;++i)
    #pragma unroll
    for (int j=0;j<4;++j)
      #pragma unroll
      for (int r=0;r<4;++r){
        size_t row = m0 + 64*wm + 16*i + (lane>>4)*4 + r;
        size_t col = n0 + 64*wn + 16*j + (lane&15);
        float v = acc[i][j][r];
        if (Cf) Cf[row*1024 + col] = v;
        else    Cb[row*1024 + col] = (bf16)v;
      }
}

// ---------------------------------------------------------------- K2: dt/alpha/beta projections (fp32)
__global__ __launch_bounds__(256) void k_alphabeta(const float* __restrict__ x,
    const float* __restrict__ WaT, const float* __restrict__ WbT,
    const float* __restrict__ A_log, const float* __restrict__ dt_bias,
    float* __restrict__ logA, float* __restrict__ betap){
  __shared__ float xl[8*1024];
  const int tid = threadIdx.x;
  const size_t base4 = (size_t)blockIdx.x * 2048;
  #pragma unroll
  for (int j=0;j<8;++j)
    ((float4*)xl)[tid + j*256] = ((const float4*)x)[base4 + tid + j*256];
  __syncthreads();
  const int r = tid >> 5, o = tid & 31;
  const float4* wrow = (const float4*)((o < 16) ? (WaT + (size_t)o*1024) : (WbT + (size_t)(o-16)*1024));
  const float4* xr = (const float4*)(xl + r*1024);
  float a0=0,a1=0,a2=0,a3=0;
  for (int j=0;j<256;++j){
    float4 xv = xr[j]; float4 wv = wrow[j];
    a0 += xv.x*wv.x; a1 += xv.y*wv.y; a2 += xv.z*wv.z; a3 += xv.w*wv.w;
  }
  float dot = (a0+a1)+(a2+a3);
  const size_t t = (size_t)blockIdx.x*8 + r;
  if (o < 16){
    float z = dot + dt_bias[o];
    float dt = (z > 20.f) ? z : log1pf(expf(z));
    logA[t*16 + o] = -expf(A_log[o]) * dt;          // log(alpha_t)
  } else {
    betap[t*16 + (o-16)] = 1.f/(1.f + expf(-dot));  // beta_t
  }
}

// ---------------------------------------------------------------- K2b (BIG): in-place fp32 l2norm of q (/8) and k
__global__ __launch_bounds__(256) void k_norm_f32(float* __restrict__ qf, float* __restrict__ kf){
  const size_t p = (size_t)blockIdx.x*256 + threadIdx.x;  // (token,head)
  {
    float4* q4 = (float4*)(qf + p*64);
    float4 v[16]; float s = 0.f;
    #pragma unroll
    for (int i=0;i<16;++i){ v[i]=q4[i]; s += v[i].x*v[i].x + v[i].y*v[i].y + v[i].z*v[i].z + v[i].w*v[i].w; }
    float sc = 0.125f / fmaxf(sqrtf(s), 1e-12f);
    #pragma unroll
    for (int i=0;i<16;++i){ v[i].x*=sc; v[i].y*=sc; v[i].z*=sc; v[i].w*=sc; q4[i]=v[i]; }
  }
  {
    float4* k4 = (float4*)(kf + p*64);
    float4 v[16]; float s = 0.f;
    #pragma unroll
    for (int i=0;i<16;++i){ v[i]=k4[i]; s += v[i].x*v[i].x + v[i].y*v[i].y + v[i].z*v[i].z + v[i].w*v[i].w; }
    float sc = 1.0f / fmaxf(sqrtf(s), 1e-12f);
    #pragma unroll
    for (int i=0;i<16;++i){ v[i].x*=sc; v[i].y*=sc; v[i].z*=sc; v[i].w*=sc; k4[i]=v[i]; }
  }
}

// ---------------------------------------------------------------- K2b (SMALL): in-place bf16 l2norm
__global__ __launch_bounds__(256) void k_norm_b16(bf16* __restrict__ qb, bf16* __restrict__ kb){
  const size_t p = (size_t)blockIdx.x*256 + threadIdx.x;
  bf16* q = qb + p*64;
  bf16* k = kb + p*64;
  bf16x8 qv[8], kv[8];
  float sq = 0.f, sk = 0.f;
  #pragma unroll
  for (int i=0;i<8;++i){
    qv[i] = ((const bf16x8*)q)[i];
    kv[i] = ((const bf16x8*)k)[i];
    #pragma unroll
    for (int j=0;j<8;++j){ float a=(float)qv[i][j]; sq+=a*a; float b=(float)kv[i][j]; sk+=b*b; }
  }
  float scq = 0.125f / fmaxf(sqrtf(sq), 1e-12f);
  float sck = 1.0f   / fmaxf(sqrtf(sk), 1e-12f);
  #pragma unroll
  for (int i=0;i<8;++i){
    bf16x8 oq, ok;
    #pragma unroll
    for (int j=0;j<8;++j){ oq[j]=(bf16)((float)qv[i][j]*scq); ok[j]=(bf16)((float)kv[i][j]*sck); }
    ((bf16x8*)q)[i] = oq; ((bf16x8*)k)[i] = ok;
  }
}

// helper: load a 64x64 head-tile (fp32 or bf16 source) and split into hi/lo LDS planes
__device__ __forceinline__ void load_split_tile(const float* f32, const bf16* b16,
                                                size_t tokbase, int h,
                                                bf16* Lh, bf16* Ll, int tid, int nthr){
  for (int i = tid; i < 1024; i += nthr){
    int t = i >> 4, c4 = (i & 15)*4;
    const size_t g = (tokbase + t)*1024 + (size_t)h*64 + c4;
    float4 v;
    if (f32) v = *(const float4*)&f32[g];
    else { bf16x4 b = *(const bf16x4*)&b16[g]; v.x=(float)b[0]; v.y=(float)b[1]; v.z=(float)b[2]; v.w=(float)b[3]; }
    bf16x4 hh, ll;
    bf2 s0 = split2(v.x); hh[0]=s0.h; ll[0]=s0.l;
    bf2 s1 = split2(v.y); hh[1]=s1.h; ll[1]=s1.l;
    bf2 s2 = split2(v.z); hh[2]=s2.h; ll[2]=s2.l;
    bf2 s3 = split2(v.w); hh[3]=s3.h; ll[3]=s3.l;
    *(bf16x4*)&Lh[t*64 + c4] = hh;
    *(bf16x4*)&Ll[t*64 + c4] = ll;
  }
}

// ---------------------------------------------------------------- K3: phase A, per chunk-head (2048 blocks, 128 thr)
__global__ __launch_bounds__(128) void k_phaseA(const float* __restrict__ kf32, const bf16* __restrict__ kb16,
    const float* __restrict__ vf, const float* __restrict__ logA, const float* __restrict__ betap,
    bf16* __restrict__ Wg, bf16* __restrict__ Dg, float* __restrict__ Pg, bf16* __restrict__ Bg){
  __shared__ bf16  Kh[64*64], Klo[64*64];
  __shared__ float E[64*64];
  __shared__ float DsolT[64*64];   // [c_v][t]
  __shared__ float WsolT[64*64];   // [c_k][t]
  __shared__ float lg_s[64], bet_s[64], gl_s[64];
  const int tid = threadIdx.x, lane = tid & 63, wid = tid >> 6;
  const int c = blockIdx.x, h = blockIdx.y, b = blockIdx.z;
  const size_t tokbase = (size_t)b*4096 + (size_t)c*64;
  const size_t cbase = ((size_t)((b*16 + h)*64 + c)) * 4096;

  load_split_tile(kf32, kb16, tokbase, h, Kh, Klo, tid, 128);
  if (tid < 64){
    float la = logA[(tokbase + tid)*16 + h];
    #pragma unroll
    for (int dlt = 1; dlt < 64; dlt <<= 1){
      float o = __shfl_up(la, dlt);
      if (lane >= dlt) la += o;
    }
    lg_s[tid] = la;                               // inclusive cumsum of log(alpha)
    bet_s[tid] = betap[(tokbase + tid)*16 + h];
  }
  __syncthreads();
  if (tid < 64) gl_s[tid] = __expf(lg_s[63] - lg_s[tid]);   // gamma_L/gamma_t

  // E[t][tau] = (gamma_t/gamma_tau) * (k_t . k_tau), strictly lower; else 0  (3-product)
  #pragma unroll
  for (int tt = 0; tt < 2; ++tt){
    const int t0 = 32*wid + 16*tt;
    #pragma unroll
    for (int tu = 0; tu < 4; ++tu){
      f32x4 accm = f32x4_zero();
      #pragma unroll
      for (int kk = 0; kk < 2; ++kk){
        bf16x8 aH = frag64(Kh,  t0,    kk, lane);
        bf16x8 aL = frag64(Klo, t0,    kk, lane);
        bf16x8 bH = frag64(Kh,  16*tu, kk, lane);
        bf16x8 bL = frag64(Klo, 16*tu, kk, lane);
        accm = mfma16x16x32(aH, bH, accm);
        accm = mfma16x16x32(aH, bL, accm);
        accm = mfma16x16x32(aL, bH, accm);
      }
      #pragma unroll
      for (int r = 0; r < 4; ++r){
        int row = t0 + (lane>>4)*4 + r, col = 16*tu + (lane&15);
        E[row*64 + col] = (col < row) ? accm[r]*__expf(lg_s[row] - lg_s[col]) : 0.f;
      }
    }
  }
  __syncthreads();

  // forward substitution: (I + diag(beta) E) X = diag(beta) RHS. wave0: RHS=V, wave1: RHS=K_hat
  {
    float Xv[64];
    if (wid == 0){
      #pragma unroll
      for (int t = 0; t < 64; ++t)
        Xv[t] = vf[(tokbase + t)*1024 + h*64 + lane];
    } else {
      #pragma unroll
      for (int t = 0; t < 64; ++t)
        Xv[t] = __expf(lg_s[t]) * ((float)Kh[t*64 + lane] + (float)Klo[t*64 + lane]);
    }
    float d[64];
    #pragma unroll
    for (int i = 0; i < 64; ++i) d[i] = 0.f;
    float* solT = wid ? WsolT : DsolT;
    #pragma unroll
    for (int t = 0; t < 64; ++t){
      float a0=0,a1=0,a2=0,a3=0;
      #pragma unroll
      for (int r4 = 0; r4 < 16; ++r4){
        float4 e = *(const float4*)&E[t*64 + r4*4];
        a0 += e.x * d[r4*4+0];
        a1 += e.y * d[r4*4+1];
        a2 += e.z * d[r4*4+2];
        a3 += e.w * d[r4*4+3];
      }
      float dv = bet_s[t] * (Xv[t] - ((a0+a1)+(a2+a3)));
      d[t] = dv;
      solT[lane*64 + t] = dv;
    }
  }
  __syncthreads();

  // P = gamma_L I - W_hat^T K_til (stored transposed, fp32), B = Dloc^T K_til (bf16)
  {
    const int j = lane;
    float kt[64];
    #pragma unroll
    for (int t = 0; t < 64; ++t)
      kt[t] = gl_s[t] * ((float)Kh[t*64 + j] + (float)Klo[t*64 + j]);
    const float gLtot = __expf(lg_s[63]);
    for (int ii = 0; ii < 32; ++ii){
      const int i = wid*32 + ii;
      float aP0=0,aP1=0,aP2=0,aP3=0, aB0=0,aB1=0,aB2=0,aB3=0;
      #pragma unroll
      for (int t4 = 0; t4 < 16; ++t4){
        float4 wv = *(const float4*)&WsolT[i*64 + t4*4];
        float4 dv = *(const float4*)&DsolT[i*64 + t4*4];
        aP0 += wv.x*kt[t4*4+0]; aP1 += wv.y*kt[t4*4+1];
        aP2 += wv.z*kt[t4*4+2]; aP3 += wv.w*kt[t4*4+3];
        aB0 += dv.x*kt[t4*4+0]; aB1 += dv.y*kt[t4*4+1];
        aB2 += dv.z*kt[t4*4+2]; aB3 += dv.w*kt[t4*4+3];
      }
      float Pv = ((i == j) ? gLtot : 0.f) - ((aP0+aP1)+(aP2+aP3));
      float Bv = (aB0+aB1)+(aB2+aB3);
      Pg[cbase + (size_t)j*64 + i] = Pv;          // P^T layout [j][i], fp32
      Bg[cbase + (size_t)i*64 + j] = (bf16)Bv;    // natural [i][j]
    }
  }
  // store W_hat, Dloc in natural [t][c] layout (bf16)
  for (int q = 0; q < 32; ++q){
    int lin = tid*32 + q;
    int t = lin >> 6, cc = lin & 63;
    Wg[cbase + lin] = (bf16)WsolT[cc*64 + t];
    Dg[cbase + lin] = (bf16)DsolT[cc*64 + t];
  }
}

// ---------------------------------------------------------------- K4: phase B, sequential cross-chunk state (32 blocks)
__global__ __launch_bounds__(256) void k_phaseB(const float* __restrict__ Pg, const bf16* __restrict__ Bg,
                                                float* __restrict__ S0g){
  __shared__ float Sf[64*64];
  __shared__ bf16 Sh[64*64], Sl[64*64];
  __shared__ bf16 Ph[64*64], Pl[64*64];
  const int tid = threadIdx.x, lane = tid & 63, w = tid >> 6;
  const size_t bid = blockIdx.x;
  for (int i = tid; i < 4096; i += 256) Sf[i] = 0.f;
  __syncthreads();
  for (int c = 0; c < 64; ++c){
    const size_t cb = (bid*64 + c)*4096;
    for (int i = tid; i < 1024; i += 256){
      float4 sv = ((const float4*)Sf)[i];
      ((float4*)(S0g + cb))[i] = sv;      // state before chunk c, fp32
      bf16x4 sh, sl;
      bf2 t0 = split2(sv.x); sh[0]=t0.h; sl[0]=t0.l;
      bf2 t1 = split2(sv.y); sh[1]=t1.h; sl[1]=t1.l;
      bf2 t2 = split2(sv.z); sh[2]=t2.h; sl[2]=t2.l;
      bf2 t3 = split2(sv.w); sh[3]=t3.h; sl[3]=t3.l;
      ((bf16x4*)Sh)[i] = sh; ((bf16x4*)Sl)[i] = sl;
      float4 pv = ((const float4*)(Pg + cb))[i];
      bf16x4 ph, pl;
      bf2 u0 = split2(pv.x); ph[0]=u0.h; pl[0]=u0.l;
      bf2 u1 = split2(pv.y); ph[1]=u1.h; pl[1]=u1.l;
      bf2 u2 = split2(pv.z); ph[2]=u2.h; pl[2]=u2.l;
      bf2 u3 = split2(pv.w); ph[3]=u3.h; pl[3]=u3.l;
      ((bf16x4*)Ph)[i] = ph; ((bf16x4*)Pl)[i] = pl;
    }
    __syncthreads();
    float ov[4][4];
    #pragma unroll
    for (int tj = 0; tj < 4; ++tj){
      f32x4 t = f32x4_zero();
      #pragma unroll
      for (int kk = 0; kk < 2; ++kk){
        bf16x8 aH = frag64(Sh, 16*w, kk, lane);
        bf16x8 aL = frag64(Sl, 16*w, kk, lane);
        bf16x8 bH = frag64(Ph, 16*tj, kk, lane);
        bf16x8 bL = frag64(Pl, 16*tj, kk, lane);
        t = mfma16x16x32(aH, bH, t);
        t = mfma16x16x32(aH, bL, t);
        t = mfma16x16x32(aL, bH, t);
      }
      #pragma unroll
      for (int r = 0; r < 4; ++r){
        int row = 16*w + (lane>>4)*4 + r, col = 16*tj + (lane&15);
        ov[tj][r] = t[r] + (float)Bg[cb + (size_t)row*64 + col];
      }
    }
    __syncthreads();
    #pragma unroll
    for (int tj = 0; tj < 4; ++tj)
      #pragma unroll
      for (int r = 0; r < 4; ++r){
        int row = 16*w + (lane>>4)*4 + r, col = 16*tj + (lane&15);
        Sf[row*64 + col] = ov[tj][r];
      }
    __syncthreads();
  }
}

// ---------------------------------------------------------------- K5: phase C, outputs + fused RMSNorm/gate (2048 blocks)
__global__ __launch_bounds__(256) void k_phaseC(
    const float* __restrict__ qf32, const bf16* __restrict__ qb16,
    const float* __restrict__ kf32, const bf16* __restrict__ kb16,
    const bf16* __restrict__ gf, const float* __restrict__ logA,
    const float* __restrict__ S0g, const bf16* __restrict__ Wg, const bf16* __restrict__ Dg,
    const float* __restrict__ rms_w, bf16* __restrict__ yh, bf16* __restrict__ yl){
  __shared__ bf16 Qh[64*64], Ql[64*64], Kh[64*64], Klo[64*64];
  __shared__ bf16 Wl_[64*64], Dl_[64*64];
  __shared__ bf16 S0h[64*64], S0l[64*64];
  __shared__ bf16 AAg[64*64];   // masked Gamma .* (Q K^T)
  __shared__ bf16 BDt[64*64];   // D_hat^T - (S0 W^T)  [i][tau]
  __shared__ float lg_s[64], gq_s[64];
  const int tid = threadIdx.x, lane = tid & 63, w = tid >> 6;
  const int c = blockIdx.x, h = blockIdx.y, b = blockIdx.z;
  const size_t tokbase = (size_t)b*4096 + (size_t)c*64;
  const size_t cbase = ((size_t)((b*16 + h)*64 + c)) * 4096;

  load_split_tile(qf32, qb16, tokbase, h, Qh, Ql, tid, 256);
  load_split_tile(kf32, kb16, tokbase, h, Kh, Klo, tid, 256);
  for (int i = tid; i < 512; i += 256){
    ((uint4*)Wl_)[i] = ((const uint4*)(Wg + cbase))[i];
    ((uint4*)Dl_)[i] = ((const uint4*)(Dg + cbase))[i];
  }
  for (int i = tid; i < 1024; i += 256){
    float4 v = ((const float4*)(S0g + cbase))[i];
    bf16x4 sh, sl;
    bf2 t0 = split2(v.x); sh[0]=t0.h; sl[0]=t0.l;
    bf2 t1 = split2(v.y); sh[1]=t1.h; sl[1]=t1.l;
    bf2 t2 = split2(v.z); sh[2]=t2.h; sl[2]=t2.l;
    bf2 t3 = split2(v.w); sh[3]=t3.h; sl[3]=t3.l;
    ((bf16x4*)S0h)[i] = sh; ((bf16x4*)S0l)[i] = sl;
  }
  if (tid < 64){
    float la = logA[(tokbase + tid)*16 + h];
    #pragma unroll
    for (int dlt = 1; dlt < 64; dlt <<= 1){
      float o = __shfl_up(la, dlt);
      if (lane >= dlt) la += o;
    }
    lg_s[tid] = la;
    gq_s[tid] = __expf(la);
  }
  __syncthreads();

  { // AAg = mask_incl(Gamma .* QK^T), 3-product
    const int t0 = 16*w;
    #pragma unroll
    for (int tu = 0; tu < 4; ++tu){
      f32x4 accm = f32x4_zero();
      #pragma unroll
      for (int kk = 0; kk < 2; ++kk){
        bf16x8 aH = frag64(Qh,  t0,    kk, lane);
        bf16x8 aL = frag64(Ql,  t0,    kk, lane);
        bf16x8 bH = frag64(Kh,  16*tu, kk, lane);
        bf16x8 bL = frag64(Klo, 16*tu, kk, lane);
        accm = mfma16x16x32(aH, bH, accm);
        accm = mfma16x16x32(aH, bL, accm);
        accm = mfma16x16x32(aL, bH, accm);
      }
      #pragma unroll
      for (int r = 0; r < 4; ++r){
        int row = t0 + (lane>>4)*4 + r, col = 16*tu + (lane&15);
        float v = (col <= row) ? accm[r]*__expf(lg_s[row] - lg_s[col]) : 0.f;
        AAg[row*64 + col] = (bf16)v;
      }
    }
  }
  { // BDt[i][tau] = Dloc[tau][i] - (S0 W_hat^T)[i][tau]   (S0 split, W single)
    const int i0 = 16*w;
    #pragma unroll
    for (int tu = 0; tu < 4; ++tu){
      f32x4 accm = f32x4_zero();
      #pragma unroll
      for (int kk = 0; kk < 2; ++kk){
        bf16x8 aH = frag64(S0h, i0,    kk, lane);
        bf16x8 aL = frag64(S0l, i0,    kk, lane);
        bf16x8 bb = frag64(Wl_, 16*tu, kk, lane);
        accm = mfma16x16x32(aH, bb, accm);
        accm = mfma16x16x32(aL, bb, accm);
      }
      #pragma unroll
      for (int r = 0; r < 4; ++r){
        int row = i0 + (lane>>4)*4 + r, col = 16*tu + (lane&15);
        float v = (float)Dl_[col*64 + row] - accm[r];
        BDt[row*64 + col] = (bf16)v;
      }
    }
  }
  __syncthreads();
  // Q_hat = gamma_t * q_t, re-split hi/lo in place
  for (int i = tid; i < 4096; i += 256){
    int t = i >> 6;
    float v = gq_s[t] * ((float)Qh[i] + (float)Ql[i]);
    bf2 sp = split2(v);
    Qh[i] = sp.h; Ql[i] = sp.l;
  }
  __syncthreads();
  { // O = Q_hat S0^T (3-product) + AAg BDt ; epilogue RMSNorm*rms_w*silu(gate) -> y hi/lo
    const int t0 = 16*w;
    f32x4 o_acc[4];
    #pragma unroll
    for (int it = 0; it < 4; ++it) o_acc[it] = f32x4_zero();
    #pragma unroll
    for (int kk = 0; kk < 2; ++kk){
      bf16x8 aQh = frag64(Qh, t0, kk, lane);
      bf16x8 aQl = frag64(Ql, t0, kk, lane);
      bf16x8 aA  = frag64(AAg, t0, kk, lane);
      #pragma unroll
      for (int it = 0; it < 4; ++it){
        bf16x8 bSh = frag64(S0h, 16*it, kk, lane);
        bf16x8 bSl = frag64(S0l, 16*it, kk, lane);
        bf16x8 bD  = frag64(BDt, 16*it, kk, lane);
        f32x4 t = o_acc[it];
        t = mfma16x16x32(aQh, bSh, t);
        t = mfma16x16x32(aQh, bSl, t);
        t = mfma16x16x32(aQl, bSh, t);
        t = mfma16x16x32(aA,  bD,  t);
        o_acc[it] = t;
      }
    }
    float rw[4];
    #pragma unroll
    for (int it = 0; it < 4; ++it) rw[it] = rms_w[16*it + (lane&15)];
    #pragma unroll
    for (int r = 0; r < 4; ++r){
      float ss = 0.f;
      #pragma unroll
      for (int it = 0; it < 4; ++it) ss += o_acc[it][r]*o_acc[it][r];
      ss += __shfl_xor(ss, 1); ss += __shfl_xor(ss, 2);
      ss += __shfl_xor(ss, 4); ss += __shfl_xor(ss, 8);
      const float scale = rsqrtf(ss*(1.f/64.f) + 1e-6f);
      const int row = t0 + (lane>>4)*4 + r;
      const size_t tok = tokbase + row;
      #pragma unroll
      for (int it = 0; it < 4; ++it){
        const int col = 16*it + (lane&15);
        float g = (float)gf[tok*1024 + h*64 + col];
        float sg = g / (1.f + __expf(-g));
        float v = o_acc[it][r]*scale*rw[it]*sg;
        bf2 sp = split2(v);
        yh[tok*1024 + h*64 + col] = sp.h;
        yl[tok*1024 + h*64 + col] = sp.l;
      }
    }
  }
}

// ---------------------------------------------------------------- launcher
extern "C" void kernel_launch(void* const* d_in, const int* in_sizes, int n_in,
                              void* d_out, int out_size, void* d_ws, size_t ws_size,
                              hipStream_t stream){
  const float* x     = (const float*)d_in[0];
  const float* Wq    = (const float*)d_in[1];
  const float* Wk    = (const float*)d_in[2];
  const float* Wv    = (const float*)d_in[3];
  const float* Wa    = (const float*)d_in[4];
  const float* Wb    = (const float*)d_in[5];
  const float* A_log = (const float*)d_in[6];
  const float* dt_b  = (const float*)d_in[7];
  const float* Wgt   = (const float*)d_in[8];
  const float* Wo    = (const float*)d_in[9];
  const float* rms_w = (const float*)d_in[10];

  // BIG mode needs ~206.8e6 B of workspace; SMALL needs ~173.2e6 B
  // (SMALL is <= the round-1-proven floor of 179.4e6 B, so it always fits).
  const bool BIG = ws_size >= (size_t)215000000;

  char* ws = (char*)d_ws;
  size_t off = 0;
  auto alloc = [&](size_t bytes)->char*{
    char* p = ws + off;
    off += (bytes + 255) & ~(size_t)255;
    return p;
  };
  const size_t PLANE = (size_t)8192*1024*2;   // bf16 activation plane (16 MiB)
  const size_t WPL   = (size_t)1024*1024*2;   // bf16 weight plane (2 MiB)
  bf16* xh  = (bf16*)alloc(PLANE);            // region also hosts Pg (A->B), then yh
  bf16* xl  = (bf16*)alloc(PLANE);            // region also hosts Pg tail, then yl
  bf16* wqh = (bf16*)alloc(WPL); bf16* wql = (bf16*)alloc(WPL);   // wqh..wgl (16 MiB
  bf16* wkh = (bf16*)alloc(WPL); bf16* wkl = (bf16*)alloc(WPL);   //  contiguous) also
  bf16* wvh = (bf16*)alloc(WPL); bf16* wvl = (bf16*)alloc(WPL);   //  hosts Bg (A->B)
  bf16* wgh = (bf16*)alloc(WPL); bf16* wgl = (bf16*)alloc(WPL);
  bf16* woh = (bf16*)alloc(WPL); bf16* wol = (bf16*)alloc(WPL);
  float* WaT = (float*)alloc((size_t)16*1024*4);
  float* WbT = (float*)alloc((size_t)16*1024*4);
  float* qf = nullptr; bf16* qb = nullptr;
  float* kf = nullptr; bf16* kb = nullptr;
  if (BIG){ qf = (float*)alloc((size_t)8192*1024*4); kf = (float*)alloc((size_t)8192*1024*4); }
  else    { qb = (bf16*) alloc(PLANE);               kb = (bf16*) alloc(PLANE); }
  float* vf  = (float*)alloc((size_t)8192*1024*4);  // dead after phase A -> hosts S0g
  bf16* gfb  = (bf16*)alloc(PLANE);
  float* logA  = (float*)alloc((size_t)8192*16*4);
  float* betap = (float*)alloc((size_t)8192*16*4);
  bf16* Wg  = (bf16*)alloc((size_t)2048*4096*2);
  bf16* Dg  = (bf16*)alloc((size_t)2048*4096*2);
  float* Pg  = (float*)xh;   // 32 MiB fp32: xh+xl region, dead between GEMMs and phase C
  float* S0g = vf;           // 32 MiB fp32: vf dead after phase A
  bf16* Bg   = wqh;          // 16 MiB bf16: wqh..wgl dead after projection GEMMs
  bf16* yh = xh;             // phase C output planes (Pg dead after phase B)
  bf16* yl = xl;

  k_cvt_x<<<8192, 256, 0, stream>>>(x, xh, xl, 2097152);
  k_transpose_w<<<dim3(32,32), 256, 0, stream>>>(Wq,  wqh, wql);
  k_transpose_w<<<dim3(32,32), 256, 0, stream>>>(Wk,  wkh, wkl);
  k_transpose_w<<<dim3(32,32), 256, 0, stream>>>(Wv,  wvh, wvl);
  k_transpose_w<<<dim3(32,32), 256, 0, stream>>>(Wgt, wgh, wgl);
  k_transpose_w<<<dim3(32,32), 256, 0, stream>>>(Wo,  woh, wol);
  k_transpose_ab<<<64, 256, 0, stream>>>(Wa, Wb, WaT, WbT);

  if (BIG){
    k_gemm3<<<dim3(64,8), 256, 0, stream>>>(xh, xl, wqh, wql, nullptr, qf);
    k_gemm3<<<dim3(64,8), 256, 0, stream>>>(xh, xl, wkh, wkl, nullptr, kf);
  } else {
    k_gemm3<<<dim3(64,8), 256, 0, stream>>>(xh, xl, wqh, wql, qb, nullptr);
    k_gemm3<<<dim3(64,8), 256, 0, stream>>>(xh, xl, wkh, wkl, kb, nullptr);
  }
  k_gemm3<<<dim3(64,8), 256, 0, stream>>>(xh, xl, wvh, wvl, nullptr, vf);
  k_gemm3<<<dim3(64,8), 256, 0, stream>>>(xh, xl, wgh, wgl, gfb, nullptr);

  k_alphabeta<<<1024, 256, 0, stream>>>(x, WaT, WbT, A_log, dt_b, logA, betap);
  if (BIG) k_norm_f32<<<512, 256, 0, stream>>>(qf, kf);
  else     k_norm_b16<<<512, 256, 0, stream>>>(qb, kb);

  k_phaseA<<<dim3(64,16,2), 128, 0, stream>>>(kf, kb, vf, logA, betap, Wg, Dg, Pg, Bg);
  k_phaseB<<<32, 256, 0, stream>>>(Pg, Bg, S0g);
  k_phaseC<<<dim3(64,16,2), 256, 0, stream>>>(qf, qb, kf, kb, gfb, logA, S0g, Wg, Dg, rms_w, yh, yl);

  k_gemm3<<<dim3(64,8), 256, 0, stream>>>(yh, yl, woh, wol, nullptr, (float*)d_out);
}

// Round 5
// 868.993 us; speedup vs baseline: 1.1569x; 1.1569x over previous
//
#include <hip/hip_runtime.h>
#include <cstdint>
#include <cstddef>

typedef __bf16 bf16;
typedef __bf16 bf16x4 __attribute__((ext_vector_type(4)));
typedef __bf16 bf16x8 __attribute__((ext_vector_type(8)));
typedef float  f32x4  __attribute__((ext_vector_type(4)));

#define GLD_LDS16(gp, lp) \
  __builtin_amdgcn_global_load_lds((__attribute__((address_space(1))) void*)(gp), \
                                   (__attribute__((address_space(3))) void*)(lp), 16, 0, 0)

__device__ __forceinline__ f32x4 f32x4_zero(){ f32x4 v; v[0]=0.f; v[1]=0.f; v[2]=0.f; v[3]=0.f; return v; }

__device__ __forceinline__ f32x4 mfma16x16x32(bf16x8 a, bf16x8 b, f32x4 c){
  return __builtin_amdgcn_mfma_f32_16x16x32_bf16(a, b, c, 0, 0, 0);
}
// fragment of a 64-col bf16 LDS array (stride 64), A/B-operand layout for 16x16x32
__device__ __forceinline__ bf16x8 frag64(const bf16* base, int row0, int kk, int lane){
  return *(const bf16x8*)&base[(row0 + (lane&15))*64 + kk*32 + (lane>>4)*8];
}
// same but arbitrary row stride (stride*2 bytes must be 16B-aligned; 72 works)
__device__ __forceinline__ bf16x8 fragS(const bf16* base, int row0, int kk, int lane, int stride){
  return *(const bf16x8*)&base[(row0 + (lane&15))*stride + kk*32 + (lane>>4)*8];
}
struct bf2 { bf16 h, l; };
__device__ __forceinline__ bf2 split2(float v){
  bf2 r; r.h = (bf16)v; r.l = (bf16)(v - (float)r.h); return r;
}

// ---------------------------------------------------------------- K0a: x -> hi/lo bf16 planes
__global__ __launch_bounds__(256) void k_cvt_x(const float* __restrict__ x,
                                               bf16* __restrict__ xh, bf16* __restrict__ xl, int n4){
  int i = blockIdx.x*256 + threadIdx.x;
  if (i < n4){
    float4 v = ((const float4*)x)[i];
    bf16x4 h, l;
    bf2 t0 = split2(v.x); h[0]=t0.h; l[0]=t0.l;
    bf2 t1 = split2(v.y); h[1]=t1.h; l[1]=t1.l;
    bf2 t2 = split2(v.z); h[2]=t2.h; l[2]=t2.l;
    bf2 t3 = split2(v.w); h[3]=t3.h; l[3]=t3.l;
    ((bf16x4*)xh)[i] = h;
    ((bf16x4*)xl)[i] = l;
  }
}

// ---------------------------------------------------------------- K0b: W[k][n] -> Wt hi/lo [n][k]
__global__ __launch_bounds__(256) void k_transpose_w(const float* __restrict__ W,
                                                     bf16* __restrict__ Wth, bf16* __restrict__ Wtl){
  __shared__ float tile[32][33];
  const int k0 = blockIdx.x*32, n0 = blockIdx.y*32;
  const int r = threadIdx.x >> 3, c4 = (threadIdx.x & 7)*4;
  float4 v = *(const float4*)&W[(size_t)(k0+r)*1024 + n0 + c4];
  tile[r][c4+0]=v.x; tile[r][c4+1]=v.y; tile[r][c4+2]=v.z; tile[r][c4+3]=v.w;
  __syncthreads();
  bf16x4 h, l;
  bf2 t0 = split2(tile[c4+0][r]); h[0]=t0.h; l[0]=t0.l;
  bf2 t1 = split2(tile[c4+1][r]); h[1]=t1.h; l[1]=t1.l;
  bf2 t2 = split2(tile[c4+2][r]); h[2]=t2.h; l[2]=t2.l;
  bf2 t3 = split2(tile[c4+3][r]); h[3]=t3.h; l[3]=t3.l;
  *(bf16x4*)&Wth[(size_t)(n0+r)*1024 + k0 + c4] = h;
  *(bf16x4*)&Wtl[(size_t)(n0+r)*1024 + k0 + c4] = l;
}

// ---------------------------------------------------------------- K0c: Walpha/Wbeta [1024][16] -> [16][1024] fp32
__global__ __launch_bounds__(256) void k_transpose_ab(const float* __restrict__ Wa, const float* __restrict__ Wb,
                                                      float* __restrict__ WaT, float* __restrict__ WbT){
  int p = blockIdx.x*256 + threadIdx.x;
  if (p < 16384){
    int o = p >> 10, k = p & 1023;
    WaT[p] = Wa[k*16 + o];
    WbT[p] = Wb[k*16 + o];
  }
}

// ---------------------------------------------------------------- K1: split-bf16 MFMA GEMM (3-product), K=1024
__global__ __launch_bounds__(256) void k_gemm3(const bf16* __restrict__ Ah, const bf16* __restrict__ Al,
                                               const bf16* __restrict__ Bth, const bf16* __restrict__ Btl,
                                               bf16* __restrict__ Cb, float* __restrict__ Cf){
  __shared__ bf16 Ash[128*32], Asl[128*32];
  __shared__ bf16 Bsh[128*32], Bsl[128*32];
  const int tid = threadIdx.x, lane = tid & 63, w = tid >> 6;
  const int wm = w >> 1, wn = w & 1;
  const size_t m0 = (size_t)blockIdx.x * 128;
  const size_t n0 = (size_t)blockIdx.y * 128;
  f32x4 acc[4][4];
  #pragma unroll
  for (int i=0;i<4;++i)
    #pragma unroll
    for (int j=0;j<4;++j) acc[i][j] = f32x4_zero();

  for (int k0 = 0; k0 < 1024; k0 += 32){
    __syncthreads();
    #pragma unroll
    for (int j = 0; j < 2; ++j){
      const int rbase = 32*w + 16*j;
      const int r = rbase + (lane >> 2);
      const int kk = k0 + (lane & 3)*8;
      GLD_LDS16(&Ah [(m0 + r)*1024 + kk], &Ash[rbase*32]);
      GLD_LDS16(&Al [(m0 + r)*1024 + kk], &Asl[rbase*32]);
      GLD_LDS16(&Bth[(n0 + r)*1024 + kk], &Bsh[rbase*32]);
      GLD_LDS16(&Btl[(n0 + r)*1024 + kk], &Bsl[rbase*32]);
    }
    __syncthreads();
    bf16x8 ah[4], al[4], bh[4], bl[4];
    #pragma unroll
    for (int t=0;t<4;++t){
      ah[t] = *(const bf16x8*)&Ash[(64*wm + 16*t + (lane&15))*32 + (lane>>4)*8];
      al[t] = *(const bf16x8*)&Asl[(64*wm + 16*t + (lane&15))*32 + (lane>>4)*8];
      bh[t] = *(const bf16x8*)&Bsh[(64*wn + 16*t + (lane&15))*32 + (lane>>4)*8];
      bl[t] = *(const bf16x8*)&Bsl[(64*wn + 16*t + (lane&15))*32 + (lane>>4)*8];
    }
    #pragma unroll
    for (int i=0;i<4;++i)
      #pragma unroll
      for (int j=0;j<4;++j){
        f32x4 t = acc[i][j];
        t = mfma16x16x32(ah[i], bh[j], t);
        t = mfma16x16x32(ah[i], bl[j], t);
        t = mfma16x16x32(al[i], bh[j], t);
        acc[i][j] = t;
      }
  }
  #pragma unroll
  for (int i=0;i<4;++i)
    #pragma unroll
    for (int j=0;j<4;++j)
      #pragma unroll
      for (int r=0;r<4;++r){
        size_t row = m0 + 64*wm + 16*i + (lane>>4)*4 + r;
        size_t col = n0 + 64*wn + 16*j + (lane&15);
        float v = acc[i][j][r];
        if (Cf) Cf[row*1024 + col] = v;
        else    Cb[row*1024 + col] = (bf16)v;
      }
}

// ---------------------------------------------------------------- K1b: single-bf16 MFMA GEMM, K=1024
__global__ __launch_bounds__(256) void k_gemm1(const bf16* __restrict__ Ah, const bf16* __restrict__ Bth,
                                               bf16* __restrict__ Cb, float* __restrict__ Cf){
  __shared__ bf16 Ash[128*32];
  __shared__ bf16 Bsh[128*32];
  const int tid = threadIdx.x, lane = tid & 63, w = tid >> 6;
  const int wm = w >> 1, wn = w & 1;
  const size_t m0 = (size_t)blockIdx.x * 128;
  const size_t n0 = (size_t)blockIdx.y * 128;
  f32x4 acc[4][4];
  #pragma unroll
  for (int i=0;i<4;++i)
    #pragma unroll
    for (int j=0;j<4;++j) acc[i][j] = f32x4_zero();

  for (int k0 = 0; k0 < 1024; k0 += 32){
    __syncthreads();
    #pragma unroll
    for (int j = 0; j < 2; ++j){
      const int rbase = 32*w + 16*j;
      const int r = rbase + (lane >> 2);
      const int kk = k0 + (lane & 3)*8;
      GLD_LDS16(&Ah [(m0 + r)*1024 + kk], &Ash[rbase*32]);
      GLD_LDS16(&Bth[(n0 + r)*1024 + kk], &Bsh[rbase*32]);
    }
    __syncthreads();
    bf16x8 ah[4], bh[4];
    #pragma unroll
    for (int t=0;t<4;++t){
      ah[t] = *(const bf16x8*)&Ash[(64*wm + 16*t + (lane&15))*32 + (lane>>4)*8];
      bh[t] = *(const bf16x8*)&Bsh[(64*wn + 16*t + (lane&15))*32 + (lane>>4)*8];
    }
    #pragma unroll
    for (int i=0;i<4;++i)
      #pragma unroll
      for (int j=0;j<4;++j)
        acc[i][j] = mfma16x16x32(ah[i], bh[j], acc[i][j]);
  }
  #pragma unroll
  for (int i=0;i<4;++i)
    #pragma unroll
    for (int j=0;j<4;++j)
      #pragma unroll
      for (int r=0;r<4;++r){
        size_t row = m0 + 64*wm + 16*i + (lane>>4)*4 + r;
        size_t col = n0 + 64*wn + 16*j + (lane&15);
        float v = acc[i][j][r];
        if (Cf) Cf[row*1024 + col] = v;
        else    Cb[row*1024 + col] = (bf16)v;
      }
}

// ---------------------------------------------------------------- K2: dt/alpha/beta projections (fp32)
__global__ __launch_bounds__(256) void k_alphabeta(const float* __restrict__ x,
    const float* __restrict__ WaT, const float* __restrict__ WbT,
    const float* __restrict__ A_log, const float* __restrict__ dt_bias,
    float* __restrict__ logA, float* __restrict__ betap){
  __shared__ float xl[8*1024];
  const int tid = threadIdx.x;
  const size_t base4 = (size_t)blockIdx.x * 2048;
  #pragma unroll
  for (int j=0;j<8;++j)
    ((float4*)xl)[tid + j*256] = ((const float4*)x)[base4 + tid + j*256];
  __syncthreads();
  const int r = tid >> 5, o = tid & 31;
  const float4* wrow = (const float4*)((o < 16) ? (WaT + (size_t)o*1024) : (WbT + (size_t)(o-16)*1024));
  const float4* xr = (const float4*)(xl + r*1024);
  float a0=0,a1=0,a2=0,a3=0;
  for (int j=0;j<256;++j){
    float4 xv = xr[j]; float4 wv = wrow[j];
    a0 += xv.x*wv.x; a1 += xv.y*wv.y; a2 += xv.z*wv.z; a3 += xv.w*wv.w;
  }
  float dot = (a0+a1)+(a2+a3);
  const size_t t = (size_t)blockIdx.x*8 + r;
  if (o < 16){
    float z = dot + dt_bias[o];
    float dt = (z > 20.f) ? z : log1pf(expf(z));
    logA[t*16 + o] = -expf(A_log[o]) * dt;          // log(alpha_t)
  } else {
    betap[t*16 + (o-16)] = 1.f/(1.f + expf(-dot));  // beta_t
  }
}

// ---------------------------------------------------------------- K2b (BIG): in-place fp32 l2norm of q (/8) and k
__global__ __launch_bounds__(256) void k_norm_f32(float* __restrict__ qf, float* __restrict__ kf){
  const size_t p = (size_t)blockIdx.x*256 + threadIdx.x;  // (token,head)
  {
    float4* q4 = (float4*)(qf + p*64);
    float4 v[16]; float s = 0.f;
    #pragma unroll
    for (int i=0;i<16;++i){ v[i]=q4[i]; s += v[i].x*v[i].x + v[i].y*v[i].y + v[i].z*v[i].z + v[i].w*v[i].w; }
    float sc = 0.125f / fmaxf(sqrtf(s), 1e-12f);
    #pragma unroll
    for (int i=0;i<16;++i){ v[i].x*=sc; v[i].y*=sc; v[i].z*=sc; v[i].w*=sc; q4[i]=v[i]; }
  }
  {
    float4* k4 = (float4*)(kf + p*64);
    float4 v[16]; float s = 0.f;
    #pragma unroll
    for (int i=0;i<16;++i){ v[i]=k4[i]; s += v[i].x*v[i].x + v[i].y*v[i].y + v[i].z*v[i].z + v[i].w*v[i].w; }
    float sc = 1.0f / fmaxf(sqrtf(s), 1e-12f);
    #pragma unroll
    for (int i=0;i<16;++i){ v[i].x*=sc; v[i].y*=sc; v[i].z*=sc; v[i].w*=sc; k4[i]=v[i]; }
  }
}

// ---------------------------------------------------------------- K2b (SMALL): in-place bf16 l2norm
__global__ __launch_bounds__(256) void k_norm_b16(bf16* __restrict__ qb, bf16* __restrict__ kb){
  const size_t p = (size_t)blockIdx.x*256 + threadIdx.x;
  bf16* q = qb + p*64;
  bf16* k = kb + p*64;
  bf16x8 qv[8], kv[8];
  float sq = 0.f, sk = 0.f;
  #pragma unroll
  for (int i=0;i<8;++i){
    qv[i] = ((const bf16x8*)q)[i];
    kv[i] = ((const bf16x8*)k)[i];
    #pragma unroll
    for (int j=0;j<8;++j){ float a=(float)qv[i][j]; sq+=a*a; float b=(float)kv[i][j]; sk+=b*b; }
  }
  float scq = 0.125f / fmaxf(sqrtf(sq), 1e-12f);
  float sck = 1.0f   / fmaxf(sqrtf(sk), 1e-12f);
  #pragma unroll
  for (int i=0;i<8;++i){
    bf16x8 oq, ok;
    #pragma unroll
    for (int j=0;j<8;++j){ oq[j]=(bf16)((float)qv[i][j]*scq); ok[j]=(bf16)((float)kv[i][j]*sck); }
    ((bf16x8*)q)[i] = oq; ((bf16x8*)k)[i] = ok;
  }
}

// helper: load a 64x64 head-tile (fp32 or bf16 source) and split into hi/lo LDS planes (stride 64)
__device__ __forceinline__ void load_split_tile(const float* f32, const bf16* b16,
                                                size_t tokbase, int h,
                                                bf16* Lh, bf16* Ll, int tid, int nthr){
  for (int i = tid; i < 1024; i += nthr){
    int t = i >> 4, c4 = (i & 15)*4;
    const size_t g = (tokbase + t)*1024 + (size_t)h*64 + c4;
    float4 v;
    if (f32) v = *(const float4*)&f32[g];
    else { bf16x4 b = *(const bf16x4*)&b16[g]; v.x=(float)b[0]; v.y=(float)b[1]; v.z=(float)b[2]; v.w=(float)b[3]; }
    bf16x4 hh, ll;
    bf2 s0 = split2(v.x); hh[0]=s0.h; ll[0]=s0.l;
    bf2 s1 = split2(v.y); hh[1]=s1.h; ll[1]=s1.l;
    bf2 s2 = split2(v.z); hh[2]=s2.h; ll[2]=s2.l;
    bf2 s3 = split2(v.w); hh[3]=s3.h; ll[3]=s3.l;
    *(bf16x4*)&Lh[t*64 + c4] = hh;
    *(bf16x4*)&Ll[t*64 + c4] = ll;
  }
}

// ---------------------------------------------------------------- K3: phase A v2 (2048 blocks, 128 thr)
// blocked forward substitution, stores out of loop, P/B via MFMA.
__global__ __launch_bounds__(128) void k_phaseA(const float* __restrict__ kf32, const bf16* __restrict__ kb16,
    const float* __restrict__ vf, const float* __restrict__ logA, const float* __restrict__ betap,
    bf16* __restrict__ Wg, bf16* __restrict__ Dg, float* __restrict__ Pg, bf16* __restrict__ Bg){
  __shared__ bf16  Kh[64*64], Kl_[64*64];
  __shared__ float Ef[64*64];
  __shared__ bf16  KtT[64*72];   // K_til^T [j][t], single bf16, stride 72
  __shared__ bf16  WT [64*72];   // Wsol^T  [i][t]
  __shared__ bf16  DT [64*72];   // Dsol^T  [i][t]
  __shared__ float lg_s[64], bet_s[64];
  const int tid = threadIdx.x, lane = tid & 63, wid = tid >> 6;
  const int c = blockIdx.x, h = blockIdx.y, b = blockIdx.z;
  const size_t tokbase = (size_t)b*4096 + (size_t)c*64;
  const size_t cbase = ((size_t)((b*16 + h)*64 + c)) * 4096;

  load_split_tile(kf32, kb16, tokbase, h, Kh, Kl_, tid, 128);
  if (tid < 64){
    float la = logA[(tokbase + tid)*16 + h];
    #pragma unroll
    for (int dlt = 1; dlt < 64; dlt <<= 1){
      float o = __shfl_up(la, dlt);
      if (lane >= dlt) la += o;
    }
    lg_s[tid] = la;                               // inclusive cumsum of log(alpha)
    bet_s[tid] = betap[(tokbase + tid)*16 + h];
  }
  __syncthreads();

  // E[t][tau] = (gamma_t/gamma_tau)*(k_t . k_tau), strictly lower; else 0  (3-product MFMA)
  #pragma unroll
  for (int tt = 0; tt < 2; ++tt){
    const int t0 = 32*wid + 16*tt;
    #pragma unroll
    for (int tu = 0; tu < 4; ++tu){
      f32x4 accm = f32x4_zero();
      #pragma unroll
      for (int kk = 0; kk < 2; ++kk){
        bf16x8 aH = frag64(Kh,  t0,    kk, lane);
        bf16x8 aL = frag64(Kl_, t0,    kk, lane);
        bf16x8 bH = frag64(Kh,  16*tu, kk, lane);
        bf16x8 bL = frag64(Kl_, 16*tu, kk, lane);
        accm = mfma16x16x32(aH, bH, accm);
        accm = mfma16x16x32(aH, bL, accm);
        accm = mfma16x16x32(aL, bH, accm);
      }
      #pragma unroll
      for (int r = 0; r < 4; ++r){
        int row = t0 + (lane>>4)*4 + r, col = 16*tu + (lane&15);
        Ef[row*64 + col] = (col < row) ? accm[r]*__expf(lg_s[row] - lg_s[col]) : 0.f;
      }
    }
  }
  // K_til^T[j][t] = (gamma_L/gamma_t) * k[t][j]  (single bf16)
  for (int i = tid; i < 4096; i += 128){
    int t = i & 63, j = i >> 6;
    float kv = (float)Kh[t*64 + j] + (float)Kl_[t*64 + j];
    KtT[j*72 + t] = (bf16)(__expf(lg_s[63] - lg_s[t]) * kv);
  }
  __syncthreads();

  // blocked forward substitution: (I + diag(beta)E) X = diag(beta) R
  // wave0: R=V -> Dsol ; wave1: R=K_hat -> Wsol. d[] stays in registers.
  {
    float Xv[64], d[64];
    if (wid == 0){
      #pragma unroll
      for (int t = 0; t < 64; ++t)
        Xv[t] = vf[(tokbase + t)*1024 + h*64 + lane];
    } else {
      #pragma unroll
      for (int t = 0; t < 64; ++t)
        Xv[t] = __expf(lg_s[t]) * ((float)Kh[t*64 + lane] + (float)Kl_[t*64 + lane]);
    }
    #pragma unroll
    for (int bi = 0; bi < 4; ++bi){
      // cross-block contributions (dependency-free, pipelines)
      float pre[16];
      #pragma unroll
      for (int tt = 0; tt < 16; ++tt){
        const int t = 16*bi + tt;
        float a0=0.f,a1=0.f,a2=0.f,a3=0.f;
        #pragma unroll
        for (int r4 = 0; r4 < 4*bi; ++r4){
          float4 e = *(const float4*)&Ef[t*64 + r4*4];
          a0 += e.x * d[r4*4+0];
          a1 += e.y * d[r4*4+1];
          a2 += e.z * d[r4*4+2];
          a3 += e.w * d[r4*4+3];
        }
        pre[tt] = (a0+a1)+(a2+a3);
      }
      // short serial diagonal solve
      #pragma unroll
      for (int tt = 0; tt < 16; ++tt){
        const int t = 16*bi + tt;
        float s = pre[tt];
        #pragma unroll
        for (int j = 0; j < 16; ++j)
          if (j < tt) s += Ef[t*64 + 16*bi + j] * d[16*bi + j];
        d[t] = bet_s[t] * (Xv[t] - s);
      }
    }
    // write transposed solution to LDS once (stride 72), + natural-layout global
    bf16* myT = wid ? WT : DT;
    #pragma unroll
    for (int s4 = 0; s4 < 16; ++s4){
      bf16x4 v4;
      v4[0]=(bf16)d[s4*4+0]; v4[1]=(bf16)d[s4*4+1];
      v4[2]=(bf16)d[s4*4+2]; v4[3]=(bf16)d[s4*4+3];
      *(bf16x4*)&myT[lane*72 + s4*4] = v4;
    }
    bf16* myG = wid ? Wg : Dg;
    #pragma unroll
    for (int t = 0; t < 64; ++t)
      myG[cbase + (size_t)t*64 + lane] = (bf16)d[t];
  }
  __syncthreads();

  // P^T[j][i] = gamma_L*I - sum_t K_til[t][j]*Wsol[t][i]  (wave0, MFMA, fp32 out)
  // B[i][j]   =              sum_t Dsol[t][i]*K_til[t][j]  (wave1, MFMA, bf16 out)
  const float gL = __expf(lg_s[63]);
  if (wid == 0){
    #pragma unroll
    for (int tj = 0; tj < 4; ++tj)
      #pragma unroll
      for (int ti = 0; ti < 4; ++ti){
        f32x4 acc = f32x4_zero();
        #pragma unroll
        for (int kk = 0; kk < 2; ++kk)
          acc = mfma16x16x32(fragS(KtT, 16*tj, kk, lane, 72), fragS(WT, 16*ti, kk, lane, 72), acc);
        #pragma unroll
        for (int r = 0; r < 4; ++r){
          int row = 16*tj + (lane>>4)*4 + r, col = 16*ti + (lane&15);
          Pg[cbase + (size_t)row*64 + col] = ((row == col) ? gL : 0.f) - acc[r];
        }
      }
  } else {
    #pragma unroll
    for (int ti = 0; ti < 4; ++ti)
      #pragma unroll
      for (int tj = 0; tj < 4; ++tj){
        f32x4 acc = f32x4_zero();
        #pragma unroll
        for (int kk = 0; kk < 2; ++kk)
          acc = mfma16x16x32(fragS(DT, 16*ti, kk, lane, 72), fragS(KtT, 16*tj, kk, lane, 72), acc);
        #pragma unroll
        for (int r = 0; r < 4; ++r){
          int row = 16*ti + (lane>>4)*4 + r, col = 16*tj + (lane&15);
          Bg[cbase + (size_t)row*64 + col] = (bf16)acc[r];
        }
      }
  }
}

// ---------------------------------------------------------------- K4: phase B, sequential cross-chunk state (32 blocks)
__global__ __launch_bounds__(256) void k_phaseB(const float* __restrict__ Pg, const bf16* __restrict__ Bg,
                                                float* __restrict__ S0g){
  __shared__ float Sf[64*64];
  __shared__ bf16 Sh[64*64], Sl[64*64];
  __shared__ bf16 Ph[64*64], Pl[64*64];
  const int tid = threadIdx.x, lane = tid & 63, w = tid >> 6;
  const size_t bid = blockIdx.x;
  for (int i = tid; i < 4096; i += 256) Sf[i] = 0.f;
  __syncthreads();
  for (int c = 0; c < 64; ++c){
    const size_t cb = (bid*64 + c)*4096;
    for (int i = tid; i < 1024; i += 256){
      float4 sv = ((const float4*)Sf)[i];
      ((float4*)(S0g + cb))[i] = sv;      // state before chunk c, fp32
      bf16x4 sh, sl;
      bf2 t0 = split2(sv.x); sh[0]=t0.h; sl[0]=t0.l;
      bf2 t1 = split2(sv.y); sh[1]=t1.h; sl[1]=t1.l;
      bf2 t2 = split2(sv.z); sh[2]=t2.h; sl[2]=t2.l;
      bf2 t3 = split2(sv.w); sh[3]=t3.h; sl[3]=t3.l;
      ((bf16x4*)Sh)[i] = sh; ((bf16x4*)Sl)[i] = sl;
      float4 pv = ((const float4*)(Pg + cb))[i];
      bf16x4 ph, pl;
      bf2 u0 = split2(pv.x); ph[0]=u0.h; pl[0]=u0.l;
      bf2 u1 = split2(pv.y); ph[1]=u1.h; pl[1]=u1.l;
      bf2 u2 = split2(pv.z); ph[2]=u2.h; pl[2]=u2.l;
      bf2 u3 = split2(pv.w); ph[3]=u3.h; pl[3]=u3.l;
      ((bf16x4*)Ph)[i] = ph; ((bf16x4*)Pl)[i] = pl;
    }
    __syncthreads();
    float ov[4][4];
    #pragma unroll
    for (int tj = 0; tj < 4; ++tj){
      f32x4 t = f32x4_zero();
      #pragma unroll
      for (int kk = 0; kk < 2; ++kk){
        bf16x8 aH = frag64(Sh, 16*w, kk, lane);
        bf16x8 aL = frag64(Sl, 16*w, kk, lane);
        bf16x8 bH = frag64(Ph, 16*tj, kk, lane);
        bf16x8 bL = frag64(Pl, 16*tj, kk, lane);
        t = mfma16x16x32(aH, bH, t);
        t = mfma16x16x32(aH, bL, t);
        t = mfma16x16x32(aL, bH, t);
      }
      #pragma unroll
      for (int r = 0; r < 4; ++r){
        int row = 16*w + (lane>>4)*4 + r, col = 16*tj + (lane&15);
        ov[tj][r] = t[r] + (float)Bg[cb + (size_t)row*64 + col];
      }
    }
    __syncthreads();
    #pragma unroll
    for (int tj = 0; tj < 4; ++tj)
      #pragma unroll
      for (int r = 0; r < 4; ++r){
        int row = 16*w + (lane>>4)*4 + r, col = 16*tj + (lane&15);
        Sf[row*64 + col] = ov[tj][r];
      }
    __syncthreads();
  }
}

// ---------------------------------------------------------------- K5: phase C, outputs + fused RMSNorm/gate (2048 blocks)
__global__ __launch_bounds__(256) void k_phaseC(
    const float* __restrict__ qf32, const bf16* __restrict__ qb16,
    const float* __restrict__ kf32, const bf16* __restrict__ kb16,
    const bf16* __restrict__ gf, const float* __restrict__ logA,
    const float* __restrict__ S0g, const bf16* __restrict__ Wg, const bf16* __restrict__ Dg,
    const float* __restrict__ rms_w, bf16* __restrict__ yh, bf16* __restrict__ yl){
  __shared__ bf16 Qh[64*64], Ql[64*64], Kh[64*64], Klo[64*64];
  __shared__ bf16 Wl_[64*64], Dl_[64*64];
  __shared__ bf16 S0h[64*64], S0l[64*64];
  __shared__ bf16 AAg[64*64];   // masked Gamma .* (Q K^T)
  __shared__ bf16 BDt[64*64];   // D_hat^T - (S0 W^T)  [i][tau]
  __shared__ float lg_s[64], gq_s[64];
  const int tid = threadIdx.x, lane = tid & 63, w = tid >> 6;
  const int c = blockIdx.x, h = blockIdx.y, b = blockIdx.z;
  const size_t tokbase = (size_t)b*4096 + (size_t)c*64;
  const size_t cbase = ((size_t)((b*16 + h)*64 + c)) * 4096;

  load_split_tile(qf32, qb16, tokbase, h, Qh, Ql, tid, 256);
  load_split_tile(kf32, kb16, tokbase, h, Kh, Klo, tid, 256);
  for (int i = tid; i < 512; i += 256){
    ((uint4*)Wl_)[i] = ((const uint4*)(Wg + cbase))[i];
    ((uint4*)Dl_)[i] = ((const uint4*)(Dg + cbase))[i];
  }
  for (int i = tid; i < 1024; i += 256){
    float4 v = ((const float4*)(S0g + cbase))[i];
    bf16x4 sh, sl;
    bf2 t0 = split2(v.x); sh[0]=t0.h; sl[0]=t0.l;
    bf2 t1 = split2(v.y); sh[1]=t1.h; sl[1]=t1.l;
    bf2 t2 = split2(v.z); sh[2]=t2.h; sl[2]=t2.l;
    bf2 t3 = split2(v.w); sh[3]=t3.h; sl[3]=t3.l;
    ((bf16x4*)S0h)[i] = sh; ((bf16x4*)S0l)[i] = sl;
  }
  if (tid < 64){
    float la = logA[(tokbase + tid)*16 + h];
    #pragma unroll
    for (int dlt = 1; dlt < 64; dlt <<= 1){
      float o = __shfl_up(la, dlt);
      if (lane >= dlt) la += o;
    }
    lg_s[tid] = la;
    gq_s[tid] = __expf(la);
  }
  __syncthreads();

  { // AAg = mask_incl(Gamma .* QK^T), 3-product
    const int t0 = 16*w;
    #pragma unroll
    for (int tu = 0; tu < 4; ++tu){
      f32x4 accm = f32x4_zero();
      #pragma unroll
      for (int kk = 0; kk < 2; ++kk){
        bf16x8 aH = frag64(Qh,  t0,    kk, lane);
        bf16x8 aL = frag64(Ql,  t0,    kk, lane);
        bf16x8 bH = frag64(Kh,  16*tu, kk, lane);
        bf16x8 bL = frag64(Klo, 16*tu, kk, lane);
        accm = mfma16x16x32(aH, bH, accm);
        accm = mfma16x16x32(aH, bL, accm);
        accm = mfma16x16x32(aL, bH, accm);
      }
      #pragma unroll
      for (int r = 0; r < 4; ++r){
        int row = t0 + (lane>>4)*4 + r, col = 16*tu + (lane&15);
        float v = (col <= row) ? accm[r]*__expf(lg_s[row] - lg_s[col]) : 0.f;
        AAg[row*64 + col] = (bf16)v;
      }
    }
  }
  { // BDt[i][tau] = Dloc[tau][i] - (S0 W_hat^T)[i][tau]   (S0 split, W single)
    const int i0 = 16*w;
    #pragma unroll
    for (int tu = 0; tu < 4; ++tu){
      f32x4 accm = f32x4_zero();
      #pragma unroll
      for (int kk = 0; kk < 2; ++kk){
        bf16x8 aH = frag64(S0h, i0,    kk, lane);
        bf16x8 aL = frag64(S0l, i0,    kk, lane);
        bf16x8 bb = frag64(Wl_, 16*tu, kk, lane);
        accm = mfma16x16x32(aH, bb, accm);
        accm = mfma16x16x32(aL, bb, accm);
      }
      #pragma unroll
      for (int r = 0; r < 4; ++r){
        int row = i0 + (lane>>4)*4 + r, col = 16*tu + (lane&15);
        float v = (float)Dl_[col*64 + row] - accm[r];
        BDt[row*64 + col] = (bf16)v;
      }
    }
  }
  __syncthreads();
  // Q_hat = gamma_t * q_t, re-split hi/lo in place
  for (int i = tid; i < 4096; i += 256){
    int t = i >> 6;
    float v = gq_s[t] * ((float)Qh[i] + (float)Ql[i]);
    bf2 sp = split2(v);
    Qh[i] = sp.h; Ql[i] = sp.l;
  }
  __syncthreads();
  { // O = Q_hat S0^T (3-product) + AAg BDt ; epilogue RMSNorm*rms_w*silu(gate) -> y hi/lo
    const int t0 = 16*w;
    f32x4 o_acc[4];
    #pragma unroll
    for (int it = 0; it < 4; ++it) o_acc[it] = f32x4_zero();
    #pragma unroll
    for (int kk = 0; kk < 2; ++kk){
      bf16x8 aQh = frag64(Qh, t0, kk, lane);
      bf16x8 aQl = frag64(Ql, t0, kk, lane);
      bf16x8 aA  = frag64(AAg, t0, kk, lane);
      #pragma unroll
      for (int it = 0; it < 4; ++it){
        bf16x8 bSh = frag64(S0h, 16*it, kk, lane);
        bf16x8 bSl = frag64(S0l, 16*it, kk, lane);
        bf16x8 bD  = frag64(BDt, 16*it, kk, lane);
        f32x4 t = o_acc[it];
        t = mfma16x16x32(aQh, bSh, t);
        t = mfma16x16x32(aQh, bSl, t);
        t = mfma16x16x32(aQl, bSh, t);
        t = mfma16x16x32(aA,  bD,  t);
        o_acc[it] = t;
      }
    }
    float rw[4];
    #pragma unroll
    for (int it = 0; it < 4; ++it) rw[it] = rms_w[16*it + (lane&15)];
    #pragma unroll
    for (int r = 0; r < 4; ++r){
      float ss = 0.f;
      #pragma unroll
      for (int it = 0; it < 4; ++it) ss += o_acc[it][r]*o_acc[it][r];
      ss += __shfl_xor(ss, 1); ss += __shfl_xor(ss, 2);
      ss += __shfl_xor(ss, 4); ss += __shfl_xor(ss, 8);
      const float scale = rsqrtf(ss*(1.f/64.f) + 1e-6f);
      const int row = t0 + (lane>>4)*4 + r;
      const size_t tok = tokbase + row;
      #pragma unroll
      for (int it = 0; it < 4; ++it){
        const int col = 16*it + (lane&15);
        float g = (float)gf[tok*1024 + h*64 + col];
        float sg = g / (1.f + __expf(-g));
        float v = o_acc[it][r]*scale*rw[it]*sg;
        bf2 sp = split2(v);
        yh[tok*1024 + h*64 + col] = sp.h;
        yl[tok*1024 + h*64 + col] = sp.l;
      }
    }
  }
}

// ---------------------------------------------------------------- launcher
extern "C" void kernel_launch(void* const* d_in, const int* in_sizes, int n_in,
                              void* d_out, int out_size, void* d_ws, size_t ws_size,
                              hipStream_t stream){
  const float* x     = (const float*)d_in[0];
  const float* Wq    = (const float*)d_in[1];
  const float* Wk    = (const float*)d_in[2];
  const float* Wv    = (const float*)d_in[3];
  const float* Wa    = (const float*)d_in[4];
  const float* Wb    = (const float*)d_in[5];
  const float* A_log = (const float*)d_in[6];
  const float* dt_b  = (const float*)d_in[7];
  const float* Wgt   = (const float*)d_in[8];
  const float* Wo    = (const float*)d_in[9];
  const float* rms_w = (const float*)d_in[10];

  const bool BIG = ws_size >= (size_t)215000000;

  char* ws = (char*)d_ws;
  size_t off = 0;
  auto alloc = [&](size_t bytes)->char*{
    char* p = ws + off;
    off += (bytes + 255) & ~(size_t)255;
    return p;
  };
  const size_t PLANE = (size_t)8192*1024*2;   // bf16 activation plane (16 MiB)
  const size_t WPL   = (size_t)1024*1024*2;   // bf16 weight plane (2 MiB)
  bf16* xh  = (bf16*)alloc(PLANE);            // region also hosts Pg (A->B), then yh
  bf16* xl  = (bf16*)alloc(PLANE);            // region also hosts Pg tail, then yl
  bf16* wqh = (bf16*)alloc(WPL); bf16* wql = (bf16*)alloc(WPL);   // wqh..wgl (16 MiB
  bf16* wkh = (bf16*)alloc(WPL); bf16* wkl = (bf16*)alloc(WPL);   //  contiguous) also
  bf16* wvh = (bf16*)alloc(WPL); bf16* wvl = (bf16*)alloc(WPL);   //  hosts Bg (A->B)
  bf16* wgh = (bf16*)alloc(WPL); bf16* wgl = (bf16*)alloc(WPL);
  bf16* woh = (bf16*)alloc(WPL); bf16* wol = (bf16*)alloc(WPL);
  float* WaT = (float*)alloc((size_t)16*1024*4);
  float* WbT = (float*)alloc((size_t)16*1024*4);
  float* qf = nullptr; bf16* qb = nullptr;
  float* kf = nullptr; bf16* kb = nullptr;
  if (BIG){ qf = (float*)alloc((size_t)8192*1024*4); kf = (float*)alloc((size_t)8192*1024*4); }
  else    { qb = (bf16*) alloc(PLANE);               kb = (bf16*) alloc(PLANE); }
  float* vf  = (float*)alloc((size_t)8192*1024*4);  // dead after phase A -> hosts S0g
  bf16* gfb  = (bf16*)alloc(PLANE);
  float* logA  = (float*)alloc((size_t)8192*16*4);
  float* betap = (float*)alloc((size_t)8192*16*4);
  bf16* Wg  = (bf16*)alloc((size_t)2048*4096*2);
  bf16* Dg  = (bf16*)alloc((size_t)2048*4096*2);
  float* Pg  = (float*)xh;   // 32 MiB fp32: xh+xl region, dead between GEMMs and phase C
  float* S0g = vf;           // 32 MiB fp32: vf dead after phase A
  bf16* Bg   = wqh;          // 16 MiB bf16: wqh..wgl dead after projection GEMMs
  bf16* yh = xh;             // phase C output planes (Pg dead after phase B)
  bf16* yl = xl;

  k_cvt_x<<<8192, 256, 0, stream>>>(x, xh, xl, 2097152);
  k_transpose_w<<<dim3(32,32), 256, 0, stream>>>(Wq,  wqh, wql);
  k_transpose_w<<<dim3(32,32), 256, 0, stream>>>(Wk,  wkh, wkl);
  k_transpose_w<<<dim3(32,32), 256, 0, stream>>>(Wv,  wvh, wvl);
  k_transpose_w<<<dim3(32,32), 256, 0, stream>>>(Wgt, wgh, wgl);
  k_transpose_w<<<dim3(32,32), 256, 0, stream>>>(Wo,  woh, wol);
  k_transpose_ab<<<64, 256, 0, stream>>>(Wa, Wb, WaT, WbT);

  if (BIG){
    k_gemm3<<<dim3(64,8), 256, 0, stream>>>(xh, xl, wqh, wql, nullptr, qf);
    k_gemm3<<<dim3(64,8), 256, 0, stream>>>(xh, xl, wkh, wkl, nullptr, kf);
  } else {
    k_gemm3<<<dim3(64,8), 256, 0, stream>>>(xh, xl, wqh, wql, qb, nullptr);
    k_gemm3<<<dim3(64,8), 256, 0, stream>>>(xh, xl, wkh, wkl, kb, nullptr);
  }
  k_gemm1<<<dim3(64,8), 256, 0, stream>>>(xh, wvh, nullptr, vf);     // v: single-bf16
  k_gemm1<<<dim3(64,8), 256, 0, stream>>>(xh, wgh, gfb, nullptr);    // gate: single-bf16

  k_alphabeta<<<1024, 256, 0, stream>>>(x, WaT, WbT, A_log, dt_b, logA, betap);
  if (BIG) k_norm_f32<<<512, 256, 0, stream>>>(qf, kf);
  else     k_norm_b16<<<512, 256, 0, stream>>>(qb, kb);

  k_phaseA<<<dim3(64,16,2), 128, 0, stream>>>(kf, kb, vf, logA, betap, Wg, Dg, Pg, Bg);
  k_phaseB<<<32, 256, 0, stream>>>(Pg, Bg, S0g);
  k_phaseC<<<dim3(64,16,2), 256, 0, stream>>>(qf, qb, kf, kb, gfb, logA, S0g, Wg, Dg, rms_w, yh, yl);

  k_gemm3<<<dim3(64,8), 256, 0, stream>>>(yh, yl, woh, wol, nullptr, (float*)d_out);
}

// Round 6
// 752.766 us; speedup vs baseline: 1.3356x; 1.1544x over previous
//
#include <hip/hip_runtime.h>
#include <cstdint>
#include <cstddef>

typedef __bf16 bf16;
typedef __bf16 bf16x4 __attribute__((ext_vector_type(4)));
typedef __bf16 bf16x8 __attribute__((ext_vector_type(8)));
typedef float  f32x4  __attribute__((ext_vector_type(4)));

#define GLD_LDS16(gp, lp) \
  __builtin_amdgcn_global_load_lds((__attribute__((address_space(1))) void*)(gp), \
                                   (__attribute__((address_space(3))) void*)(lp), 16, 0, 0)

__device__ __forceinline__ f32x4 f32x4_zero(){ f32x4 v; v[0]=0.f; v[1]=0.f; v[2]=0.f; v[3]=0.f; return v; }

__device__ __forceinline__ f32x4 mfma16x16x32(bf16x8 a, bf16x8 b, f32x4 c){
  return __builtin_amdgcn_mfma_f32_16x16x32_bf16(a, b, c, 0, 0, 0);
}
// fragment of a 64-col bf16 LDS array (stride 64), A/B-operand layout for 16x16x32
__device__ __forceinline__ bf16x8 frag64(const bf16* base, int row0, int kk, int lane){
  return *(const bf16x8*)&base[(row0 + (lane&15))*64 + kk*32 + (lane>>4)*8];
}
// same but arbitrary row stride (stride*2 bytes must be 16B-aligned; 72 works)
__device__ __forceinline__ bf16x8 fragS(const bf16* base, int row0, int kk, int lane, int stride){
  return *(const bf16x8*)&base[(row0 + (lane&15))*stride + kk*32 + (lane>>4)*8];
}
struct bf2 { bf16 h, l; };
__device__ __forceinline__ bf2 split2(float v){
  bf2 r; r.h = (bf16)v; r.l = (bf16)(v - (float)r.h); return r;
}

// ---------------------------------------------------------------- K0a: x -> hi/lo bf16 planes
__global__ __launch_bounds__(256) void k_cvt_x(const float* __restrict__ x,
                                               bf16* __restrict__ xh, bf16* __restrict__ xl, int n4){
  int i = blockIdx.x*256 + threadIdx.x;
  if (i < n4){
    float4 v = ((const float4*)x)[i];
    bf16x4 h, l;
    bf2 t0 = split2(v.x); h[0]=t0.h; l[0]=t0.l;
    bf2 t1 = split2(v.y); h[1]=t1.h; l[1]=t1.l;
    bf2 t2 = split2(v.z); h[2]=t2.h; l[2]=t2.l;
    bf2 t3 = split2(v.w); h[3]=t3.h; l[3]=t3.l;
    ((bf16x4*)xh)[i] = h;
    ((bf16x4*)xl)[i] = l;
  }
}

// ---------------------------------------------------------------- K0b: W[k][n] -> Wt hi/lo [n][k]
__global__ __launch_bounds__(256) void k_transpose_w(const float* __restrict__ W,
                                                     bf16* __restrict__ Wth, bf16* __restrict__ Wtl){
  __shared__ float tile[32][33];
  const int k0 = blockIdx.x*32, n0 = blockIdx.y*32;
  const int r = threadIdx.x >> 3, c4 = (threadIdx.x & 7)*4;
  float4 v = *(const float4*)&W[(size_t)(k0+r)*1024 + n0 + c4];
  tile[r][c4+0]=v.x; tile[r][c4+1]=v.y; tile[r][c4+2]=v.z; tile[r][c4+3]=v.w;
  __syncthreads();
  bf16x4 h, l;
  bf2 t0 = split2(tile[c4+0][r]); h[0]=t0.h; l[0]=t0.l;
  bf2 t1 = split2(tile[c4+1][r]); h[1]=t1.h; l[1]=t1.l;
  bf2 t2 = split2(tile[c4+2][r]); h[2]=t2.h; l[2]=t2.l;
  bf2 t3 = split2(tile[c4+3][r]); h[3]=t3.h; l[3]=t3.l;
  *(bf16x4*)&Wth[(size_t)(n0+r)*1024 + k0 + c4] = h;
  *(bf16x4*)&Wtl[(size_t)(n0+r)*1024 + k0 + c4] = l;
}

// ---------------------------------------------------------------- K0c: Walpha/Wbeta [1024][16] -> [16][1024] fp32
__global__ __launch_bounds__(256) void k_transpose_ab(const float* __restrict__ Wa, const float* __restrict__ Wb,
                                                      float* __restrict__ WaT, float* __restrict__ WbT){
  int p = blockIdx.x*256 + threadIdx.x;
  if (p < 16384){
    int o = p >> 10, k = p & 1023;
    WaT[p] = Wa[k*16 + o];
    WbT[p] = Wb[k*16 + o];
  }
}

// ---------------------------------------------------------------- K1: split-bf16 MFMA GEMM (3-product), K=1024
__global__ __launch_bounds__(256) void k_gemm3(const bf16* __restrict__ Ah, const bf16* __restrict__ Al,
                                               const bf16* __restrict__ Bth, const bf16* __restrict__ Btl,
                                               bf16* __restrict__ Cb, float* __restrict__ Cf){
  __shared__ bf16 Ash[128*32], Asl[128*32];
  __shared__ bf16 Bsh[128*32], Bsl[128*32];
  const int tid = threadIdx.x, lane = tid & 63, w = tid >> 6;
  const int wm = w >> 1, wn = w & 1;
  const size_t m0 = (size_t)blockIdx.x * 128;
  const size_t n0 = (size_t)blockIdx.y * 128;
  f32x4 acc[4][4];
  #pragma unroll
  for (int i=0;i<4;++i)
    #pragma unroll
    for (int j=0;j<4;++j) acc[i][j] = f32x4_zero();

  for (int k0 = 0; k0 < 1024; k0 += 32){
    __syncthreads();
    #pragma unroll
    for (int j = 0; j < 2; ++j){
      const int rbase = 32*w + 16*j;
      const int r = rbase + (lane >> 2);
      const int kk = k0 + (lane & 3)*8;
      GLD_LDS16(&Ah [(m0 + r)*1024 + kk], &Ash[rbase*32]);
      GLD_LDS16(&Al [(m0 + r)*1024 + kk], &Asl[rbase*32]);
      GLD_LDS16(&Bth[(n0 + r)*1024 + kk], &Bsh[rbase*32]);
      GLD_LDS16(&Btl[(n0 + r)*1024 + kk], &Bsl[rbase*32]);
    }
    __syncthreads();
    bf16x8 ah[4], al[4], bh[4], bl[4];
    #pragma unroll
    for (int t=0;t<4;++t){
      ah[t] = *(const bf16x8*)&Ash[(64*wm + 16*t + (lane&15))*32 + (lane>>4)*8];
      al[t] = *(const bf16x8*)&Asl[(64*wm + 16*t + (lane&15))*32 + (lane>>4)*8];
      bh[t] = *(const bf16x8*)&Bsh[(64*wn + 16*t + (lane&15))*32 + (lane>>4)*8];
      bl[t] = *(const bf16x8*)&Bsl[(64*wn + 16*t + (lane&15))*32 + (lane>>4)*8];
    }
    #pragma unroll
    for (int i=0;i<4;++i)
      #pragma unroll
      for (int j=0;j<4;++j){
        f32x4 t = acc[i][j];
        t = mfma16x16x32(ah[i], bh[j], t);
        t = mfma16x16x32(ah[i], bl[j], t);
        t = mfma16x16x32(al[i], bh[j], t);
        acc[i][j] = t;
      }
  }
  #pragma unroll
  for (int i=0;i<4;++i)
    #pragma unroll
    for (int j=0;j<4;++j)
      #pragma unroll
      for (int r=0;r<4;++r){
        size_t row = m0 + 64*wm + 16*i + (lane>>4)*4 + r;
        size_t col = n0 + 64*wn + 16*j + (lane&15);
        float v = acc[i][j][r];
        if (Cf) Cf[row*1024 + col] = v;
        else    Cb[row*1024 + col] = (bf16)v;
      }
}

// ---------------------------------------------------------------- K1b: single-bf16 MFMA GEMM, K=1024
__global__ __launch_bounds__(256) void k_gemm1(const bf16* __restrict__ Ah, const bf16* __restrict__ Bth,
                                               bf16* __restrict__ Cb, float* __restrict__ Cf){
  __shared__ bf16 Ash[128*32];
  __shared__ bf16 Bsh[128*32];
  const int tid = threadIdx.x, lane = tid & 63, w = tid >> 6;
  const int wm = w >> 1, wn = w & 1;
  const size_t m0 = (size_t)blockIdx.x * 128;
  const size_t n0 = (size_t)blockIdx.y * 128;
  f32x4 acc[4][4];
  #pragma unroll
  for (int i=0;i<4;++i)
    #pragma unroll
    for (int j=0;j<4;++j) acc[i][j] = f32x4_zero();

  for (int k0 = 0; k0 < 1024; k0 += 32){
    __syncthreads();
    #pragma unroll
    for (int j = 0; j < 2; ++j){
      const int rbase = 32*w + 16*j;
      const int r = rbase + (lane >> 2);
      const int kk = k0 + (lane & 3)*8;
      GLD_LDS16(&Ah [(m0 + r)*1024 + kk], &Ash[rbase*32]);
      GLD_LDS16(&Bth[(n0 + r)*1024 + kk], &Bsh[rbase*32]);
    }
    __syncthreads();
    bf16x8 ah[4], bh[4];
    #pragma unroll
    for (int t=0;t<4;++t){
      ah[t] = *(const bf16x8*)&Ash[(64*wm + 16*t + (lane&15))*32 + (lane>>4)*8];
      bh[t] = *(const bf16x8*)&Bsh[(64*wn + 16*t + (lane&15))*32 + (lane>>4)*8];
    }
    #pragma unroll
    for (int i=0;i<4;++i)
      #pragma unroll
      for (int j=0;j<4;++j)
        acc[i][j] = mfma16x16x32(ah[i], bh[j], acc[i][j]);
  }
  #pragma unroll
  for (int i=0;i<4;++i)
    #pragma unroll
    for (int j=0;j<4;++j)
      #pragma unroll
      for (int r=0;r<4;++r){
        size_t row = m0 + 64*wm + 16*i + (lane>>4)*4 + r;
        size_t col = n0 + 64*wn + 16*j + (lane&15);
        float v = acc[i][j][r];
        if (Cf) Cf[row*1024 + col] = v;
        else    Cb[row*1024 + col] = (bf16)v;
      }
}

// ---------------------------------------------------------------- K2: dt/alpha/beta projections (fp32)
__global__ __launch_bounds__(256) void k_alphabeta(const float* __restrict__ x,
    const float* __restrict__ WaT, const float* __restrict__ WbT,
    const float* __restrict__ A_log, const float* __restrict__ dt_bias,
    float* __restrict__ logA, float* __restrict__ betap){
  __shared__ float xl[8*1024];
  const int tid = threadIdx.x;
  const size_t base4 = (size_t)blockIdx.x * 2048;
  #pragma unroll
  for (int j=0;j<8;++j)
    ((float4*)xl)[tid + j*256] = ((const float4*)x)[base4 + tid + j*256];
  __syncthreads();
  const int r = tid >> 5, o = tid & 31;
  const float4* wrow = (const float4*)((o < 16) ? (WaT + (size_t)o*1024) : (WbT + (size_t)(o-16)*1024));
  const float4* xr = (const float4*)(xl + r*1024);
  float a0=0,a1=0,a2=0,a3=0;
  for (int j=0;j<256;++j){
    float4 xv = xr[j]; float4 wv = wrow[j];
    a0 += xv.x*wv.x; a1 += xv.y*wv.y; a2 += xv.z*wv.z; a3 += xv.w*wv.w;
  }
  float dot = (a0+a1)+(a2+a3);
  const size_t t = (size_t)blockIdx.x*8 + r;
  if (o < 16){
    float z = dot + dt_bias[o];
    float dt = (z > 20.f) ? z : log1pf(expf(z));
    logA[t*16 + o] = -expf(A_log[o]) * dt;          // log(alpha_t)
  } else {
    betap[t*16 + (o-16)] = 1.f/(1.f + expf(-dot));  // beta_t
  }
}

// ---------------------------------------------------------------- K2b (BIG): in-place fp32 l2norm of q (/8) and k
__global__ __launch_bounds__(256) void k_norm_f32(float* __restrict__ qf, float* __restrict__ kf){
  const size_t p = (size_t)blockIdx.x*256 + threadIdx.x;  // (token,head)
  {
    float4* q4 = (float4*)(qf + p*64);
    float4 v[16]; float s = 0.f;
    #pragma unroll
    for (int i=0;i<16;++i){ v[i]=q4[i]; s += v[i].x*v[i].x + v[i].y*v[i].y + v[i].z*v[i].z + v[i].w*v[i].w; }
    float sc = 0.125f / fmaxf(sqrtf(s), 1e-12f);
    #pragma unroll
    for (int i=0;i<16;++i){ v[i].x*=sc; v[i].y*=sc; v[i].z*=sc; v[i].w*=sc; q4[i]=v[i]; }
  }
  {
    float4* k4 = (float4*)(kf + p*64);
    float4 v[16]; float s = 0.f;
    #pragma unroll
    for (int i=0;i<16;++i){ v[i]=k4[i]; s += v[i].x*v[i].x + v[i].y*v[i].y + v[i].z*v[i].z + v[i].w*v[i].w; }
    float sc = 1.0f / fmaxf(sqrtf(s), 1e-12f);
    #pragma unroll
    for (int i=0;i<16;++i){ v[i].x*=sc; v[i].y*=sc; v[i].z*=sc; v[i].w*=sc; k4[i]=v[i]; }
  }
}

// ---------------------------------------------------------------- K2b (SMALL): in-place bf16 l2norm
__global__ __launch_bounds__(256) void k_norm_b16(bf16* __restrict__ qb, bf16* __restrict__ kb){
  const size_t p = (size_t)blockIdx.x*256 + threadIdx.x;
  bf16* q = qb + p*64;
  bf16* k = kb + p*64;
  bf16x8 qv[8], kv[8];
  float sq = 0.f, sk = 0.f;
  #pragma unroll
  for (int i=0;i<8;++i){
    qv[i] = ((const bf16x8*)q)[i];
    kv[i] = ((const bf16x8*)k)[i];
    #pragma unroll
    for (int j=0;j<8;++j){ float a=(float)qv[i][j]; sq+=a*a; float b=(float)kv[i][j]; sk+=b*b; }
  }
  float scq = 0.125f / fmaxf(sqrtf(sq), 1e-12f);
  float sck = 1.0f   / fmaxf(sqrtf(sk), 1e-12f);
  #pragma unroll
  for (int i=0;i<8;++i){
    bf16x8 oq, ok;
    #pragma unroll
    for (int j=0;j<8;++j){ oq[j]=(bf16)((float)qv[i][j]*scq); ok[j]=(bf16)((float)kv[i][j]*sck); }
    ((bf16x8*)q)[i] = oq; ((bf16x8*)k)[i] = ok;
  }
}

// helper: load a 64x64 head-tile (fp32 or bf16 source) and split into hi/lo LDS planes (stride 64)
__device__ __forceinline__ void load_split_tile(const float* f32, const bf16* b16,
                                                size_t tokbase, int h,
                                                bf16* Lh, bf16* Ll, int tid, int nthr){
  for (int i = tid; i < 1024; i += nthr){
    int t = i >> 4, c4 = (i & 15)*4;
    const size_t g = (tokbase + t)*1024 + (size_t)h*64 + c4;
    float4 v;
    if (f32) v = *(const float4*)&f32[g];
    else { bf16x4 b = *(const bf16x4*)&b16[g]; v.x=(float)b[0]; v.y=(float)b[1]; v.z=(float)b[2]; v.w=(float)b[3]; }
    bf16x4 hh, ll;
    bf2 s0 = split2(v.x); hh[0]=s0.h; ll[0]=s0.l;
    bf2 s1 = split2(v.y); hh[1]=s1.h; ll[1]=s1.l;
    bf2 s2 = split2(v.z); hh[2]=s2.h; ll[2]=s2.l;
    bf2 s3 = split2(v.w); hh[3]=s3.h; ll[3]=s3.l;
    *(bf16x4*)&Lh[t*64 + c4] = hh;
    *(bf16x4*)&Ll[t*64 + c4] = ll;
  }
}

// ---------------------------------------------------------------- K3: phase A (2048 blocks, 128 thr)
__global__ __launch_bounds__(128) void k_phaseA(const float* __restrict__ kf32, const bf16* __restrict__ kb16,
    const float* __restrict__ vf, const float* __restrict__ logA, const float* __restrict__ betap,
    bf16* __restrict__ Wg, bf16* __restrict__ Dg, float* __restrict__ Pg, bf16* __restrict__ Bg){
  __shared__ bf16  Kh[64*64], Kl_[64*64];
  __shared__ float Ef[64*64];
  __shared__ bf16  KtT[64*72];   // K_til^T [j][t], single bf16, stride 72
  __shared__ bf16  WT [64*72];   // Wsol^T  [i][t]
  __shared__ bf16  DT [64*72];   // Dsol^T  [i][t]
  __shared__ float lg_s[64], bet_s[64];
  const int tid = threadIdx.x, lane = tid & 63, wid = tid >> 6;
  const int c = blockIdx.x, h = blockIdx.y, b = blockIdx.z;
  const size_t tokbase = (size_t)b*4096 + (size_t)c*64;
  const size_t cbase = ((size_t)((b*16 + h)*64 + c)) * 4096;

  load_split_tile(kf32, kb16, tokbase, h, Kh, Kl_, tid, 128);
  if (tid < 64){
    float la = logA[(tokbase + tid)*16 + h];
    #pragma unroll
    for (int dlt = 1; dlt < 64; dlt <<= 1){
      float o = __shfl_up(la, dlt);
      if (lane >= dlt) la += o;
    }
    lg_s[tid] = la;                               // inclusive cumsum of log(alpha)
    bet_s[tid] = betap[(tokbase + tid)*16 + h];
  }
  __syncthreads();

  // E[t][tau] = (gamma_t/gamma_tau)*(k_t . k_tau), strictly lower; else 0  (3-product MFMA)
  #pragma unroll
  for (int tt = 0; tt < 2; ++tt){
    const int t0 = 32*wid + 16*tt;
    #pragma unroll
    for (int tu = 0; tu < 4; ++tu){
      f32x4 accm = f32x4_zero();
      #pragma unroll
      for (int kk = 0; kk < 2; ++kk){
        bf16x8 aH = frag64(Kh,  t0,    kk, lane);
        bf16x8 aL = frag64(Kl_, t0,    kk, lane);
        bf16x8 bH = frag64(Kh,  16*tu, kk, lane);
        bf16x8 bL = frag64(Kl_, 16*tu, kk, lane);
        accm = mfma16x16x32(aH, bH, accm);
        accm = mfma16x16x32(aH, bL, accm);
        accm = mfma16x16x32(aL, bH, accm);
      }
      #pragma unroll
      for (int r = 0; r < 4; ++r){
        int row = t0 + (lane>>4)*4 + r, col = 16*tu + (lane&15);
        Ef[row*64 + col] = (col < row) ? accm[r]*__expf(lg_s[row] - lg_s[col]) : 0.f;
      }
    }
  }
  // K_til^T[j][t] = (gamma_L/gamma_t) * k[t][j]  (single bf16)
  for (int i = tid; i < 4096; i += 128){
    int t = i & 63, j = i >> 6;
    float kv = (float)Kh[t*64 + j] + (float)Kl_[t*64 + j];
    KtT[j*72 + t] = (bf16)(__expf(lg_s[63] - lg_s[t]) * kv);
  }
  __syncthreads();

  // blocked forward substitution: (I + diag(beta)E) X = diag(beta) R
  {
    float Xv[64], d[64];
    if (wid == 0){
      #pragma unroll
      for (int t = 0; t < 64; ++t)
        Xv[t] = vf[(tokbase + t)*1024 + h*64 + lane];
    } else {
      #pragma unroll
      for (int t = 0; t < 64; ++t)
        Xv[t] = __expf(lg_s[t]) * ((float)Kh[t*64 + lane] + (float)Kl_[t*64 + lane]);
    }
    #pragma unroll
    for (int bi = 0; bi < 4; ++bi){
      float pre[16];
      #pragma unroll
      for (int tt = 0; tt < 16; ++tt){
        const int t = 16*bi + tt;
        float a0=0.f,a1=0.f,a2=0.f,a3=0.f;
        #pragma unroll
        for (int r4 = 0; r4 < 4*bi; ++r4){
          float4 e = *(const float4*)&Ef[t*64 + r4*4];
          a0 += e.x * d[r4*4+0];
          a1 += e.y * d[r4*4+1];
          a2 += e.z * d[r4*4+2];
          a3 += e.w * d[r4*4+3];
        }
        pre[tt] = (a0+a1)+(a2+a3);
      }
      #pragma unroll
      for (int tt = 0; tt < 16; ++tt){
        const int t = 16*bi + tt;
        float s = pre[tt];
        #pragma unroll
        for (int j = 0; j < 16; ++j)
          if (j < tt) s += Ef[t*64 + 16*bi + j] * d[16*bi + j];
        d[t] = bet_s[t] * (Xv[t] - s);
      }
    }
    bf16* myT = wid ? WT : DT;
    #pragma unroll
    for (int s4 = 0; s4 < 16; ++s4){
      bf16x4 v4;
      v4[0]=(bf16)d[s4*4+0]; v4[1]=(bf16)d[s4*4+1];
      v4[2]=(bf16)d[s4*4+2]; v4[3]=(bf16)d[s4*4+3];
      *(bf16x4*)&myT[lane*72 + s4*4] = v4;
    }
    bf16* myG = wid ? Wg : Dg;
    #pragma unroll
    for (int t = 0; t < 64; ++t)
      myG[cbase + (size_t)t*64 + lane] = (bf16)d[t];
  }
  __syncthreads();

  // P^T[j][i] = gamma_L*I - sum_t K_til[t][j]*Wsol[t][i]  (wave0, MFMA, fp32 out)
  // B[i][j]   =              sum_t Dsol[t][i]*K_til[t][j]  (wave1, MFMA, bf16 out)
  const float gL = __expf(lg_s[63]);
  if (wid == 0){
    #pragma unroll
    for (int tj = 0; tj < 4; ++tj)
      #pragma unroll
      for (int ti = 0; ti < 4; ++ti){
        f32x4 acc = f32x4_zero();
        #pragma unroll
        for (int kk = 0; kk < 2; ++kk)
          acc = mfma16x16x32(fragS(KtT, 16*tj, kk, lane, 72), fragS(WT, 16*ti, kk, lane, 72), acc);
        #pragma unroll
        for (int r = 0; r < 4; ++r){
          int row = 16*tj + (lane>>4)*4 + r, col = 16*ti + (lane&15);
          Pg[cbase + (size_t)row*64 + col] = ((row == col) ? gL : 0.f) - acc[r];
        }
      }
  } else {
    #pragma unroll
    for (int ti = 0; ti < 4; ++ti)
      #pragma unroll
      for (int tj = 0; tj < 4; ++tj){
        f32x4 acc = f32x4_zero();
        #pragma unroll
        for (int kk = 0; kk < 2; ++kk)
          acc = mfma16x16x32(fragS(DT, 16*ti, kk, lane, 72), fragS(KtT, 16*tj, kk, lane, 72), acc);
        #pragma unroll
        for (int r = 0; r < 4; ++r){
          int row = 16*ti + (lane>>4)*4 + r, col = 16*tj + (lane&15);
          Bg[cbase + (size_t)row*64 + col] = (bf16)acc[r];
        }
      }
  }
}

// ---------------------------------------------------------------- K4a: segment composition (256 blocks: 8 seg x 32 chains)
// (Pseg, Bseg) = (P_{c0},B_{c0}) ∘ ... ∘ (P_{c7},B_{c7});  Pacc/Bacc fp32 in registers.
__global__ __launch_bounds__(256) void k_phaseB1(const float* __restrict__ Pg, const bf16* __restrict__ Bg,
                                                 float* __restrict__ PsegT, float* __restrict__ BsegF){
  __shared__ bf16 PaccH[4096], PaccL[4096], BaccH[4096], BaccL[4096];
  __shared__ bf16 PcH[4096], PcL[4096];
  __shared__ bf16 BcS[4096];
  const int tid = threadIdx.x, lane = tid & 63, w = tid >> 6;
  const int seg = blockIdx.x;
  const size_t chain = blockIdx.y;
  f32x4 Pr[4], Br[4];
  #pragma unroll
  for (int it = 0; it < 4; ++it){
    #pragma unroll
    for (int r = 0; r < 4; ++r){
      int row = 16*w + (lane>>4)*4 + r, col = 16*it + (lane&15);
      Pr[it][r] = (row == col) ? 1.f : 0.f;   // Pacc = I
      Br[it][r] = 0.f;                        // Bacc = 0
    }
  }
  for (int i = 0; i < 8; ++i){
    const size_t cb = (chain*64 + (size_t)seg*8 + i)*4096;
    // write own-wave rows of Pacc/Bacc split planes
    #pragma unroll
    for (int it = 0; it < 4; ++it)
      #pragma unroll
      for (int r = 0; r < 4; ++r){
        int row = 16*w + (lane>>4)*4 + r, col = 16*it + (lane&15);
        bf2 sp = split2(Pr[it][r]); PaccH[row*64+col] = sp.h; PaccL[row*64+col] = sp.l;
        bf2 sb = split2(Br[it][r]); BaccH[row*64+col] = sb.h; BaccL[row*64+col] = sb.l;
      }
    __syncthreads();   // prev iter's MFMA done -> safe to overwrite PcH/L
    for (int j = tid; j < 1024; j += 256){
      float4 pv = ((const float4*)(Pg + cb))[j];
      bf16x4 ph, pl;
      bf2 u0 = split2(pv.x); ph[0]=u0.h; pl[0]=u0.l;
      bf2 u1 = split2(pv.y); ph[1]=u1.h; pl[1]=u1.l;
      bf2 u2 = split2(pv.z); ph[2]=u2.h; pl[2]=u2.l;
      bf2 u3 = split2(pv.w); ph[3]=u3.h; pl[3]=u3.l;
      ((bf16x4*)PcH)[j] = ph; ((bf16x4*)PcL)[j] = pl;
    }
    for (int j = tid; j < 512; j += 256)
      ((uint4*)BcS)[j] = ((const uint4*)(Bg + cb))[j];
    __syncthreads();
    f32x4 nP[4], nB[4];
    #pragma unroll
    for (int it = 0; it < 4; ++it){ nP[it] = f32x4_zero(); nB[it] = f32x4_zero(); }
    #pragma unroll
    for (int kk = 0; kk < 2; ++kk){
      bf16x8 aPH = frag64(PaccH, 16*w, kk, lane), aPL = frag64(PaccL, 16*w, kk, lane);
      bf16x8 aBH = frag64(BaccH, 16*w, kk, lane), aBL = frag64(BaccL, 16*w, kk, lane);
      #pragma unroll
      for (int it = 0; it < 4; ++it){
        bf16x8 bH = frag64(PcH, 16*it, kk, lane), bL = frag64(PcL, 16*it, kk, lane);
        nP[it] = mfma16x16x32(aPH, bH, nP[it]);
        nP[it] = mfma16x16x32(aPH, bL, nP[it]);
        nP[it] = mfma16x16x32(aPL, bH, nP[it]);
        nB[it] = mfma16x16x32(aBH, bH, nB[it]);
        nB[it] = mfma16x16x32(aBH, bL, nB[it]);
        nB[it] = mfma16x16x32(aBL, bH, nB[it]);
      }
    }
    #pragma unroll
    for (int it = 0; it < 4; ++it)
      #pragma unroll
      for (int r = 0; r < 4; ++r){
        int row = 16*w + (lane>>4)*4 + r, col = 16*it + (lane&15);
        Pr[it][r] = nP[it][r];
        Br[it][r] = nB[it][r] + (float)BcS[row*64 + col];
      }
  }
  const size_t sb = (chain*8 + seg)*4096;
  #pragma unroll
  for (int it = 0; it < 4; ++it)
    #pragma unroll
    for (int r = 0; r < 4; ++r){
      int row = 16*w + (lane>>4)*4 + r, col = 16*it + (lane&15);
      PsegT[sb + (size_t)col*64 + row] = Pr[it][r];   // transposed (B-operand layout)
      BsegF[sb + (size_t)row*64 + col] = Br[it][r];   // natural
    }
}

// ---------------------------------------------------------------- K4b: segment-level scan (32 blocks, 8 steps)
__global__ __launch_bounds__(256) void k_phaseB2(const float* __restrict__ PsegT, const float* __restrict__ BsegF,
                                                 float* __restrict__ S0g){
  __shared__ bf16 Sh[4096], Sl[4096], Ph[4096], Pl[4096];
  __shared__ float Bf[4096];
  const int tid = threadIdx.x, lane = tid & 63, w = tid >> 6;
  const size_t bid = blockIdx.x;
  f32x4 Sr[4];
  #pragma unroll
  for (int it = 0; it < 4; ++it) Sr[it] = f32x4_zero();
  for (int seg = 0; seg < 8; ++seg){
    const size_t sb  = (bid*8 + seg)*4096;
    const size_t s0b = (bid*64 + (size_t)seg*8)*4096;
    // store entry state (fp32) + write own-rows split planes
    #pragma unroll
    for (int it = 0; it < 4; ++it)
      #pragma unroll
      for (int r = 0; r < 4; ++r){
        int row = 16*w + (lane>>4)*4 + r, col = 16*it + (lane&15);
        S0g[s0b + (size_t)row*64 + col] = Sr[it][r];
        bf2 sp = split2(Sr[it][r]); Sh[row*64+col] = sp.h; Sl[row*64+col] = sp.l;
      }
    __syncthreads();
    for (int j = tid; j < 1024; j += 256){
      float4 pv = ((const float4*)(PsegT + sb))[j];
      bf16x4 ph, pl;
      bf2 u0 = split2(pv.x); ph[0]=u0.h; pl[0]=u0.l;
      bf2 u1 = split2(pv.y); ph[1]=u1.h; pl[1]=u1.l;
      bf2 u2 = split2(pv.z); ph[2]=u2.h; pl[2]=u2.l;
      bf2 u3 = split2(pv.w); ph[3]=u3.h; pl[3]=u3.l;
      ((bf16x4*)Ph)[j] = ph; ((bf16x4*)Pl)[j] = pl;
      ((float4*)Bf)[j] = ((const float4*)(BsegF + sb))[j];
    }
    __syncthreads();
    f32x4 nS[4];
    #pragma unroll
    for (int it = 0; it < 4; ++it) nS[it] = f32x4_zero();
    #pragma unroll
    for (int kk = 0; kk < 2; ++kk){
      bf16x8 aH = frag64(Sh, 16*w, kk, lane), aL = frag64(Sl, 16*w, kk, lane);
      #pragma unroll
      for (int it = 0; it < 4; ++it){
        bf16x8 bH = frag64(Ph, 16*it, kk, lane), bL = frag64(Pl, 16*it, kk, lane);
        nS[it] = mfma16x16x32(aH, bH, nS[it]);
        nS[it] = mfma16x16x32(aH, bL, nS[it]);
        nS[it] = mfma16x16x32(aL, bH, nS[it]);
      }
    }
    #pragma unroll
    for (int it = 0; it < 4; ++it)
      #pragma unroll
      for (int r = 0; r < 4; ++r){
        int row = 16*w + (lane>>4)*4 + r, col = 16*it + (lane&15);
        Sr[it][r] = nS[it][r] + Bf[row*64 + col];
      }
  }
}

// ---------------------------------------------------------------- K4c: within-segment replay (256 blocks, 7 steps)
__global__ __launch_bounds__(256) void k_phaseB3(const float* __restrict__ Pg, const bf16* __restrict__ Bg,
                                                 float* __restrict__ S0g){
  __shared__ bf16 Sh[4096], Sl[4096], Ph[4096], Pl[4096];
  __shared__ bf16 BcS[4096];
  const int tid = threadIdx.x, lane = tid & 63, w = tid >> 6;
  const int seg = blockIdx.x;
  const size_t chain = blockIdx.y;
  const size_t segbase = chain*64 + (size_t)seg*8;
  f32x4 Sr[4];
  // load segment entry state (written by B2)
  #pragma unroll
  for (int it = 0; it < 4; ++it)
    #pragma unroll
    for (int r = 0; r < 4; ++r){
      int row = 16*w + (lane>>4)*4 + r, col = 16*it + (lane&15);
      Sr[it][r] = S0g[segbase*4096 + (size_t)row*64 + col];
    }
  for (int i = 0; i < 7; ++i){
    const size_t cb = (segbase + i)*4096;
    #pragma unroll
    for (int it = 0; it < 4; ++it)
      #pragma unroll
      for (int r = 0; r < 4; ++r){
        int row = 16*w + (lane>>4)*4 + r, col = 16*it + (lane&15);
        bf2 sp = split2(Sr[it][r]); Sh[row*64+col] = sp.h; Sl[row*64+col] = sp.l;
      }
    __syncthreads();
    for (int j = tid; j < 1024; j += 256){
      float4 pv = ((const float4*)(Pg + cb))[j];
      bf16x4 ph, pl;
      bf2 u0 = split2(pv.x); ph[0]=u0.h; pl[0]=u0.l;
      bf2 u1 = split2(pv.y); ph[1]=u1.h; pl[1]=u1.l;
      bf2 u2 = split2(pv.z); ph[2]=u2.h; pl[2]=u2.l;
      bf2 u3 = split2(pv.w); ph[3]=u3.h; pl[3]=u3.l;
      ((bf16x4*)Ph)[j] = ph; ((bf16x4*)Pl)[j] = pl;
    }
    for (int j = tid; j < 512; j += 256)
      ((uint4*)BcS)[j] = ((const uint4*)(Bg + cb))[j];
    __syncthreads();
    f32x4 nS[4];
    #pragma unroll
    for (int it = 0; it < 4; ++it) nS[it] = f32x4_zero();
    #pragma unroll
    for (int kk = 0; kk < 2; ++kk){
      bf16x8 aH = frag64(Sh, 16*w, kk, lane), aL = frag64(Sl, 16*w, kk, lane);
      #pragma unroll
      for (int it = 0; it < 4; ++it){
        bf16x8 bH = frag64(Ph, 16*it, kk, lane), bL = frag64(Pl, 16*it, kk, lane);
        nS[it] = mfma16x16x32(aH, bH, nS[it]);
        nS[it] = mfma16x16x32(aH, bL, nS[it]);
        nS[it] = mfma16x16x32(aL, bH, nS[it]);
      }
    }
    const size_t outb = (segbase + i + 1)*4096;
    #pragma unroll
    for (int it = 0; it < 4; ++it)
      #pragma unroll
      for (int r = 0; r < 4; ++r){
        int row = 16*w + (lane>>4)*4 + r, col = 16*it + (lane&15);
        float v = nS[it][r] + (float)BcS[row*64 + col];
        Sr[it][r] = v;
        S0g[outb + (size_t)row*64 + col] = v;
      }
  }
}

// ---------------------------------------------------------------- K5: phase C, outputs + fused RMSNorm/gate (2048 blocks)
__global__ __launch_bounds__(256) void k_phaseC(
    const float* __restrict__ qf32, const bf16* __restrict__ qb16,
    const float* __restrict__ kf32, const bf16* __restrict__ kb16,
    const bf16* __restrict__ gf, const float* __restrict__ logA,
    const float* __restrict__ S0g, const bf16* __restrict__ Wg, const bf16* __restrict__ Dg,
    const float* __restrict__ rms_w, bf16* __restrict__ yh, bf16* __restrict__ yl){
  __shared__ bf16 Qh[64*64], Ql[64*64], Kh[64*64], Klo[64*64];
  __shared__ bf16 Wl_[64*64], Dl_[64*64];
  __shared__ bf16 S0h[64*64], S0l[64*64];
  __shared__ bf16 AAg[64*64];
  __shared__ bf16 BDt[64*64];
  __shared__ float lg_s[64], gq_s[64];
  const int tid = threadIdx.x, lane = tid & 63, w = tid >> 6;
  const int c = blockIdx.x, h = blockIdx.y, b = blockIdx.z;
  const size_t tokbase = (size_t)b*4096 + (size_t)c*64;
  const size_t cbase = ((size_t)((b*16 + h)*64 + c)) * 4096;

  load_split_tile(qf32, qb16, tokbase, h, Qh, Ql, tid, 256);
  load_split_tile(kf32, kb16, tokbase, h, Kh, Klo, tid, 256);
  for (int i = tid; i < 512; i += 256){
    ((uint4*)Wl_)[i] = ((const uint4*)(Wg + cbase))[i];
    ((uint4*)Dl_)[i] = ((const uint4*)(Dg + cbase))[i];
  }
  for (int i = tid; i < 1024; i += 256){
    float4 v = ((const float4*)(S0g + cbase))[i];
    bf16x4 sh, sl;
    bf2 t0 = split2(v.x); sh[0]=t0.h; sl[0]=t0.l;
    bf2 t1 = split2(v.y); sh[1]=t1.h; sl[1]=t1.l;
    bf2 t2 = split2(v.z); sh[2]=t2.h; sl[2]=t2.l;
    bf2 t3 = split2(v.w); sh[3]=t3.h; sl[3]=t3.l;
    ((bf16x4*)S0h)[i] = sh; ((bf16x4*)S0l)[i] = sl;
  }
  if (tid < 64){
    float la = logA[(tokbase + tid)*16 + h];
    #pragma unroll
    for (int dlt = 1; dlt < 64; dlt <<= 1){
      float o = __shfl_up(la, dlt);
      if (lane >= dlt) la += o;
    }
    lg_s[tid] = la;
    gq_s[tid] = __expf(la);
  }
  __syncthreads();

  { // AAg = mask_incl(Gamma .* QK^T), 3-product
    const int t0 = 16*w;
    #pragma unroll
    for (int tu = 0; tu < 4; ++tu){
      f32x4 accm = f32x4_zero();
      #pragma unroll
      for (int kk = 0; kk < 2; ++kk){
        bf16x8 aH = frag64(Qh,  t0,    kk, lane);
        bf16x8 aL = frag64(Ql,  t0,    kk, lane);
        bf16x8 bH = frag64(Kh,  16*tu, kk, lane);
        bf16x8 bL = frag64(Klo, 16*tu, kk, lane);
        accm = mfma16x16x32(aH, bH, accm);
        accm = mfma16x16x32(aH, bL, accm);
        accm = mfma16x16x32(aL, bH, accm);
      }
      #pragma unroll
      for (int r = 0; r < 4; ++r){
        int row = t0 + (lane>>4)*4 + r, col = 16*tu + (lane&15);
        float v = (col <= row) ? accm[r]*__expf(lg_s[row] - lg_s[col]) : 0.f;
        AAg[row*64 + col] = (bf16)v;
      }
    }
  }
  { // BDt[i][tau] = Dloc[tau][i] - (S0 W_hat^T)[i][tau]
    const int i0 = 16*w;
    #pragma unroll
    for (int tu = 0; tu < 4; ++tu){
      f32x4 accm = f32x4_zero();
      #pragma unroll
      for (int kk = 0; kk < 2; ++kk){
        bf16x8 aH = frag64(S0h, i0,    kk, lane);
        bf16x8 aL = frag64(S0l, i0,    kk, lane);
        bf16x8 bb = frag64(Wl_, 16*tu, kk, lane);
        accm = mfma16x16x32(aH, bb, accm);
        accm = mfma16x16x32(aL, bb, accm);
      }
      #pragma unroll
      for (int r = 0; r < 4; ++r){
        int row = i0 + (lane>>4)*4 + r, col = 16*tu + (lane&15);
        float v = (float)Dl_[col*64 + row] - accm[r];
        BDt[row*64 + col] = (bf16)v;
      }
    }
  }
  __syncthreads();
  for (int i = tid; i < 4096; i += 256){
    int t = i >> 6;
    float v = gq_s[t] * ((float)Qh[i] + (float)Ql[i]);
    bf2 sp = split2(v);
    Qh[i] = sp.h; Ql[i] = sp.l;
  }
  __syncthreads();
  {
    const int t0 = 16*w;
    f32x4 o_acc[4];
    #pragma unroll
    for (int it = 0; it < 4; ++it) o_acc[it] = f32x4_zero();
    #pragma unroll
    for (int kk = 0; kk < 2; ++kk){
      bf16x8 aQh = frag64(Qh, t0, kk, lane);
      bf16x8 aQl = frag64(Ql, t0, kk, lane);
      bf16x8 aA  = frag64(AAg, t0, kk, lane);
      #pragma unroll
      for (int it = 0; it < 4; ++it){
        bf16x8 bSh = frag64(S0h, 16*it, kk, lane);
        bf16x8 bSl = frag64(S0l, 16*it, kk, lane);
        bf16x8 bD  = frag64(BDt, 16*it, kk, lane);
        f32x4 t = o_acc[it];
        t = mfma16x16x32(aQh, bSh, t);
        t = mfma16x16x32(aQh, bSl, t);
        t = mfma16x16x32(aQl, bSh, t);
        t = mfma16x16x32(aA,  bD,  t);
        o_acc[it] = t;
      }
    }
    float rw[4];
    #pragma unroll
    for (int it = 0; it < 4; ++it) rw[it] = rms_w[16*it + (lane&15)];
    #pragma unroll
    for (int r = 0; r < 4; ++r){
      float ss = 0.f;
      #pragma unroll
      for (int it = 0; it < 4; ++it) ss += o_acc[it][r]*o_acc[it][r];
      ss += __shfl_xor(ss, 1); ss += __shfl_xor(ss, 2);
      ss += __shfl_xor(ss, 4); ss += __shfl_xor(ss, 8);
      const float scale = rsqrtf(ss*(1.f/64.f) + 1e-6f);
      const int row = t0 + (lane>>4)*4 + r;
      const size_t tok = tokbase + row;
      #pragma unroll
      for (int it = 0; it < 4; ++it){
        const int col = 16*it + (lane&15);
        float g = (float)gf[tok*1024 + h*64 + col];
        float sg = g / (1.f + __expf(-g));
        float v = o_acc[it][r]*scale*rw[it]*sg;
        bf2 sp = split2(v);
        yh[tok*1024 + h*64 + col] = sp.h;
        yl[tok*1024 + h*64 + col] = sp.l;
      }
    }
  }
}

// ---------------------------------------------------------------- launcher
extern "C" void kernel_launch(void* const* d_in, const int* in_sizes, int n_in,
                              void* d_out, int out_size, void* d_ws, size_t ws_size,
                              hipStream_t stream){
  const float* x     = (const float*)d_in[0];
  const float* Wq    = (const float*)d_in[1];
  const float* Wk    = (const float*)d_in[2];
  const float* Wv    = (const float*)d_in[3];
  const float* Wa    = (const float*)d_in[4];
  const float* Wb    = (const float*)d_in[5];
  const float* A_log = (const float*)d_in[6];
  const float* dt_b  = (const float*)d_in[7];
  const float* Wgt   = (const float*)d_in[8];
  const float* Wo    = (const float*)d_in[9];
  const float* rms_w = (const float*)d_in[10];

  const bool BIG = ws_size >= (size_t)215000000;

  char* ws = (char*)d_ws;
  size_t off = 0;
  auto alloc = [&](size_t bytes)->char*{
    char* p = ws + off;
    off += (bytes + 255) & ~(size_t)255;
    return p;
  };
  const size_t PLANE = (size_t)8192*1024*2;   // bf16 activation plane (16 MiB)
  const size_t WPL   = (size_t)1024*1024*2;   // bf16 weight plane (2 MiB)
  bf16* xh  = (bf16*)alloc(PLANE);            // region also hosts Pg (A->B3), then yh
  bf16* xl  = (bf16*)alloc(PLANE);
  bf16* wqh = (bf16*)alloc(WPL); bf16* wql = (bf16*)alloc(WPL);   // wqh..wgl also hosts Bg
  bf16* wkh = (bf16*)alloc(WPL); bf16* wkl = (bf16*)alloc(WPL);
  bf16* wvh = (bf16*)alloc(WPL); bf16* wvl = (bf16*)alloc(WPL);
  bf16* wgh = (bf16*)alloc(WPL); bf16* wgl = (bf16*)alloc(WPL);
  bf16* woh = (bf16*)alloc(WPL); bf16* wol = (bf16*)alloc(WPL);
  float* WaT = (float*)alloc((size_t)16*1024*4);
  float* WbT = (float*)alloc((size_t)16*1024*4);
  float* qf = nullptr; bf16* qb = nullptr;
  float* kf = nullptr; bf16* kb = nullptr;
  if (BIG){ qf = (float*)alloc((size_t)8192*1024*4); kf = (float*)alloc((size_t)8192*1024*4); }
  else    { qb = (bf16*) alloc(PLANE);               kb = (bf16*) alloc(PLANE); }
  float* vf  = (float*)alloc((size_t)8192*1024*4);  // dead after phase A -> hosts S0g
  bf16* gfb  = (bf16*)alloc(PLANE);
  float* logA  = (float*)alloc((size_t)8192*16*4);
  float* betap = (float*)alloc((size_t)8192*16*4);
  bf16* Wg  = (bf16*)alloc((size_t)2048*4096*2);
  bf16* Dg  = (bf16*)alloc((size_t)2048*4096*2);
  float* Pg  = (float*)xh;            // 33.5 MiB fp32 in xh+xl (dead between GEMMs and phase C)
  float* S0g = vf;                    // 33.5 MiB fp32 (vf dead after phase A)
  bf16* Bg   = wqh;                   // 16 MiB bf16 (projection weights dead)
  float* PsegT = (float*)d_out;       // 4 MiB scratch in d_out (overwritten by final GEMM)
  float* BsegF = (float*)d_out + 1048576;  // next 4 MiB
  bf16* yh = xh;                      // phase C outputs (Pg dead after B3)
  bf16* yl = xl;

  k_cvt_x<<<8192, 256, 0, stream>>>(x, xh, xl, 2097152);
  k_transpose_w<<<dim3(32,32), 256, 0, stream>>>(Wq,  wqh, wql);
  k_transpose_w<<<dim3(32,32), 256, 0, stream>>>(Wk,  wkh, wkl);
  k_transpose_w<<<dim3(32,32), 256, 0, stream>>>(Wv,  wvh, wvl);
  k_transpose_w<<<dim3(32,32), 256, 0, stream>>>(Wgt, wgh, wgl);
  k_transpose_w<<<dim3(32,32), 256, 0, stream>>>(Wo,  woh, wol);
  k_transpose_ab<<<64, 256, 0, stream>>>(Wa, Wb, WaT, WbT);

  if (BIG){
    k_gemm1<<<dim3(64,8), 256, 0, stream>>>(xh, wqh, nullptr, qf);
    k_gemm1<<<dim3(64,8), 256, 0, stream>>>(xh, wkh, nullptr, kf);
  } else {
    k_gemm1<<<dim3(64,8), 256, 0, stream>>>(xh, wqh, qb, nullptr);
    k_gemm1<<<dim3(64,8), 256, 0, stream>>>(xh, wkh, kb, nullptr);
  }
  k_gemm1<<<dim3(64,8), 256, 0, stream>>>(xh, wvh, nullptr, vf);
  k_gemm1<<<dim3(64,8), 256, 0, stream>>>(xh, wgh, gfb, nullptr);

  k_alphabeta<<<1024, 256, 0, stream>>>(x, WaT, WbT, A_log, dt_b, logA, betap);
  if (BIG) k_norm_f32<<<512, 256, 0, stream>>>(qf, kf);
  else     k_norm_b16<<<512, 256, 0, stream>>>(qb, kb);

  k_phaseA<<<dim3(64,16,2), 128, 0, stream>>>(kf, kb, vf, logA, betap, Wg, Dg, Pg, Bg);
  k_phaseB1<<<dim3(8,32), 256, 0, stream>>>(Pg, Bg, PsegT, BsegF);
  k_phaseB2<<<32, 256, 0, stream>>>(PsegT, BsegF, S0g);
  k_phaseB3<<<dim3(8,32), 256, 0, stream>>>(Pg, Bg, S0g);
  k_phaseC<<<dim3(64,16,2), 256, 0, stream>>>(qf, qb, kf, kb, gfb, logA, S0g, Wg, Dg, rms_w, yh, yl);

  k_gemm3<<<dim3(64,8), 256, 0, stream>>>(yh, yl, woh, wol, nullptr, (float*)d_out);
}